// Round 1
// baseline (9549.702 us; speedup 1.0000x reference)
//
#include <hip/hip_runtime.h>

#define N_ENT 100000
#define N_HE  20000
#define DD    128

// ---------------- SpMM: COO scatter with fp32 atomics ----------------
// Each 32-thread group handles one nnz; each thread covers 4 floats (float4).
__global__ __launch_bounds__(256) void spmm_atomic_kernel(
    const int* __restrict__ rows,
    const int* __restrict__ cols,
    const float* __restrict__ vals,
    const float* __restrict__ x,
    float* __restrict__ y,
    int nnz)
{
    long long gid = (long long)blockIdx.x * blockDim.x + threadIdx.x;
    long long e = gid >> 5;
    if (e >= nnz) return;
    int t = (int)(gid & 31);

    int r = rows[e];
    int c = cols[e];
    float v = vals[e];

    const float4 xv = *reinterpret_cast<const float4*>(x + (long long)c * DD + t * 4);
    float* yp = y + (long long)r * DD + t * 4;
    atomicAdd(yp + 0, v * xv.x);
    atomicAdd(yp + 1, v * xv.y);
    atomicAdd(yp + 2, v * xv.z);
    atomicAdd(yp + 3, v * xv.w);
}

// ---------------- Dense pass: out = lrelu(x @ W^T + b) (MODE 0 writes, MODE 1 accumulates) ----------------
// MODE 0: x = ego + side, out = lrelu(...)
// MODE 1: x = ego * side, out += lrelu(...)
// Per wave: 8 rows; lane l computes output cols j=l and j=l+64.
// W staged in LDS packed: Wp[k][l] = {W[l*128+k], W[(l+64)*128+k]}  (64 KB)
// x[k] broadcast via v_readlane with uniform k (no LDS traffic).
__device__ __forceinline__ float lrelu(float x) { return x > 0.0f ? x : 0.01f * x; }

template<int MODE>
__global__ __launch_bounds__(256) void dense_pass_kernel(
    const float* __restrict__ ego,
    const float* __restrict__ side,
    const float* __restrict__ W,
    const float* __restrict__ b,
    float* __restrict__ out)
{
    __shared__ float2 Wp[128 * 64];

    const int tid = threadIdx.x;

    // Stage W transposed+packed. Global reads coalesced over k.
    for (int idx = tid; idx < 128 * 64; idx += 256) {
        int l = idx >> 7;     // 0..63
        int k = idx & 127;    // 0..127
        float w0 = W[l * 128 + k];
        float w1 = W[(l + 64) * 128 + k];
        Wp[k * 64 + l] = make_float2(w0, w1);
    }
    __syncthreads();

    const int wave = tid >> 6;   // 0..3
    const int lane = tid & 63;

    const float bl0 = b[lane];
    const float bl1 = b[lane + 64];

    const int n_chunks = N_ENT / 32;  // 3125, each chunk = 32 rows (4 waves x 8 rows)

    for (int chunk = blockIdx.x; chunk < n_chunks; chunk += gridDim.x) {
        const int row0 = chunk * 32 + wave * 8;

        // Load x rows: xs0[r] = x[row][lane], xs1[r] = x[row][lane+64]
        float xs0[8], xs1[8];
#pragma unroll
        for (int r = 0; r < 8; ++r) {
            long long base = (long long)(row0 + r) * DD;
            float e0 = ego[base + lane];
            float e1 = ego[base + 64 + lane];
            float s0 = side[base + lane];
            float s1 = side[base + 64 + lane];
            if (MODE == 0) { xs0[r] = e0 + s0; xs1[r] = e1 + s1; }
            else           { xs0[r] = e0 * s0; xs1[r] = e1 * s1; }
        }

        float acc0[8], acc1[8];
#pragma unroll
        for (int r = 0; r < 8; ++r) { acc0[r] = 0.0f; acc1[r] = 0.0f; }

        // k = 0..63 uses xs0 (lane k holds x[k])
#pragma unroll 8
        for (int k = 0; k < 64; ++k) {
            float2 w = Wp[k * 64 + lane];
#pragma unroll
            for (int r = 0; r < 8; ++r) {
                float xk = __int_as_float(
                    __builtin_amdgcn_readlane(__float_as_int(xs0[r]), k));
                acc0[r] = fmaf(xk, w.x, acc0[r]);
                acc1[r] = fmaf(xk, w.y, acc1[r]);
            }
        }
        // k = 64..127 uses xs1 (lane k-64 holds x[k])
#pragma unroll 8
        for (int k = 0; k < 64; ++k) {
            float2 w = Wp[(k + 64) * 64 + lane];
#pragma unroll
            for (int r = 0; r < 8; ++r) {
                float xk = __int_as_float(
                    __builtin_amdgcn_readlane(__float_as_int(xs1[r]), k));
                acc0[r] = fmaf(xk, w.x, acc0[r]);
                acc1[r] = fmaf(xk, w.y, acc1[r]);
            }
        }

        // Epilogue
#pragma unroll
        for (int r = 0; r < 8; ++r) {
            long long base = (long long)(row0 + r) * DD;
            float o0 = lrelu(acc0[r] + bl0);
            float o1 = lrelu(acc1[r] + bl1);
            if (MODE == 0) {
                out[base + lane]      = o0;
                out[base + 64 + lane] = o1;
            } else {
                out[base + lane]      += o0;
                out[base + 64 + lane] += o1;
            }
        }
    }
}

extern "C" void kernel_launch(void* const* d_in, const int* in_sizes, int n_in,
                              void* d_out, int out_size, void* d_ws, size_t ws_size,
                              hipStream_t stream)
{
    const float* ego     = (const float*)d_in[0];
    const int*   a_rows  = (const int*)d_in[1];
    const int*   a_cols  = (const int*)d_in[2];
    const float* a_vals  = (const float*)d_in[3];
    const int*   p1_rows = (const int*)d_in[4];
    const int*   p1_cols = (const int*)d_in[5];
    const float* p1_vals = (const float*)d_in[6];
    const int*   p2_rows = (const int*)d_in[7];
    const int*   p2_cols = (const int*)d_in[8];
    const float* p2_vals = (const float*)d_in[9];
    const int*   l1_rows = (const int*)d_in[10];
    const int*   l1_cols = (const int*)d_in[11];
    const float* l1_vals = (const float*)d_in[12];
    const int*   l2_rows = (const int*)d_in[13];
    const int*   l2_cols = (const int*)d_in[14];
    const float* l2_vals = (const float*)d_in[15];
    const float* W1      = (const float*)d_in[16];
    const float* b1      = (const float*)d_in[17];
    const float* W2      = (const float*)d_in[18];
    const float* b2      = (const float*)d_in[19];

    const int nnzA = in_sizes[1];
    const int nnzH = in_sizes[4];

    float* side = (float*)d_ws;                       // N_ENT * D floats
    float* h    = side + (size_t)N_ENT * DD;          // N_HE * D floats (shared by proj/lib stage1)

    // Zero accumulators
    hipMemsetAsync(d_ws, 0,
                   ((size_t)N_ENT * DD + (size_t)N_HE * DD) * sizeof(float),
                   stream);

    auto launch_spmm = [&](const int* r, const int* c, const float* v,
                           const float* x, float* y, int nnz) {
        long long tot = (long long)nnz * 32;
        int blocks = (int)((tot + 255) / 256);
        spmm_atomic_kernel<<<blocks, 256, 0, stream>>>(r, c, v, x, y, nnz);
    };

    // side = A_in @ ego
    launch_spmm(a_rows, a_cols, a_vals, ego, side, nnzA);
    // side += p2 @ (p1 @ ego)
    launch_spmm(p1_rows, p1_cols, p1_vals, ego, h, nnzH);
    launch_spmm(p2_rows, p2_cols, p2_vals, h, side, nnzH);
    // re-zero h, then side += l2 @ (l1 @ ego)
    hipMemsetAsync(h, 0, (size_t)N_HE * DD * sizeof(float), stream);
    launch_spmm(l1_rows, l1_cols, l1_vals, ego, h, nnzH);
    launch_spmm(l2_rows, l2_cols, l2_vals, h, side, nnzH);

    // out = lrelu((ego+side) @ W1^T + b1); out += lrelu((ego*side) @ W2^T + b2)
    dense_pass_kernel<0><<<1024, 256, 0, stream>>>(ego, side, W1, b1, (float*)d_out);
    dense_pass_kernel<1><<<1024, 256, 0, stream>>>(ego, side, W2, b2, (float*)d_out);
}

// Round 2
// 1592.100 us; speedup vs baseline: 5.9982x; 5.9982x over previous
//
#include <hip/hip_runtime.h>

#define N_ENT 100000
#define N_HE  20000
#define DD    128

// ---------------- CSR build: histogram ----------------
__global__ __launch_bounds__(256) void hist_kernel(
    const int* __restrict__ rows, int* __restrict__ counts, int nnz)
{
    int i = blockIdx.x * blockDim.x + threadIdx.x;
    if (i < nnz) atomicAdd(&counts[rows[i]], 1);
}

// ---------------- CSR build: single-workgroup exclusive scan ----------------
// rp[i] = sum(counts[0..i-1]); rp[n] = total; cursor[i] = rp[i].
// counts and cursor may alias (read-before-write per element by same thread).
__global__ __launch_bounds__(1024) void scan_kernel(
    const int* __restrict__ counts, int* __restrict__ rp,
    int* __restrict__ cursor, int n)
{
    __shared__ int wsum[16];
    __shared__ int s_carry;
    const int tid = threadIdx.x;
    const int lane = tid & 63;
    const int wave = tid >> 6;
    if (tid == 0) s_carry = 0;
    __syncthreads();

    for (int base = 0; base < n; base += 1024) {
        int i = base + tid;
        int c = (i < n) ? counts[i] : 0;
        // inclusive wave scan
        int v = c;
        for (int d = 1; d < 64; d <<= 1) {
            int u = __shfl_up(v, d, 64);
            if (lane >= d) v += u;
        }
        if (lane == 63) wsum[wave] = v;
        __syncthreads();
        if (wave == 0) {
            int ws = (lane < 16) ? wsum[lane] : 0;
            for (int d = 1; d < 16; d <<= 1) {
                int u = __shfl_up(ws, d, 64);
                if (lane >= d) ws += u;
            }
            if (lane < 16) wsum[lane] = ws;  // inclusive over waves
        }
        __syncthreads();
        int waveoff = (wave == 0) ? 0 : wsum[wave - 1];
        int excl = s_carry + waveoff + (v - c);
        if (i < n) { rp[i] = excl; cursor[i] = excl; }
        __syncthreads();                 // everyone read s_carry
        if (tid == 1023) s_carry += wsum[15];
        __syncthreads();
    }
    if (tid == 0) rp[n] = s_carry;
}

// ---------------- CSR build: scatter (col,val) into row segments ----------------
__global__ __launch_bounds__(256) void scatter_kernel(
    const int* __restrict__ rows, const int* __restrict__ cols,
    const float* __restrict__ vals, int* __restrict__ cursor,
    int* __restrict__ scols, float* __restrict__ svals, int nnz)
{
    int i = blockIdx.x * blockDim.x + threadIdx.x;
    if (i >= nnz) return;
    int r = rows[i];
    int pos = atomicAdd(&cursor[r], 1);
    scols[pos] = cols[i];
    svals[pos] = vals[i];
}

// ---------------- SpMM gather: one wave per output row ----------------
__device__ __forceinline__ float bcastf(float x, int j) {
    return __int_as_float(__builtin_amdgcn_readlane(__float_as_int(x), j));
}

template<int ACCUM>
__global__ __launch_bounds__(256) void spmm_csr_kernel(
    const int* __restrict__ rp,
    const int* __restrict__ scols,
    const float* __restrict__ svals,
    const float* __restrict__ x,
    float* __restrict__ y,
    int n_rows)
{
    int wid = (int)(((long long)blockIdx.x * blockDim.x + threadIdx.x) >> 6);
    int lane = threadIdx.x & 63;
    if (wid >= n_rows) return;

    int start = rp[wid];
    int end   = rp[wid + 1];

    float acc0 = 0.0f, acc1 = 0.0f;

    for (int sb = start; sb < end; sb += 64) {
        int nn = end - sb;
        if (nn > 64) nn = 64;
        int myc = 0; float myv = 0.0f;
        if (lane < nn) {
            myc = scols[sb + lane] * DD;   // pre-scaled byte-free offset
            myv = svals[sb + lane];
        }
        int j = 0;
        for (; j + 4 <= nn; j += 4) {
            int c0 = __builtin_amdgcn_readlane(myc, j);
            int c1 = __builtin_amdgcn_readlane(myc, j + 1);
            int c2 = __builtin_amdgcn_readlane(myc, j + 2);
            int c3 = __builtin_amdgcn_readlane(myc, j + 3);
            float v0 = bcastf(myv, j);
            float v1 = bcastf(myv, j + 1);
            float v2 = bcastf(myv, j + 2);
            float v3 = bcastf(myv, j + 3);
            float a0 = x[c0 + lane],      b0 = x[c0 + 64 + lane];
            float a1 = x[c1 + lane],      b1 = x[c1 + 64 + lane];
            float a2 = x[c2 + lane],      b2 = x[c2 + 64 + lane];
            float a3 = x[c3 + lane],      b3 = x[c3 + 64 + lane];
            acc0 = fmaf(v0, a0, acc0);  acc1 = fmaf(v0, b0, acc1);
            acc0 = fmaf(v1, a1, acc0);  acc1 = fmaf(v1, b1, acc1);
            acc0 = fmaf(v2, a2, acc0);  acc1 = fmaf(v2, b2, acc1);
            acc0 = fmaf(v3, a3, acc0);  acc1 = fmaf(v3, b3, acc1);
        }
        for (; j < nn; ++j) {
            int c = __builtin_amdgcn_readlane(myc, j);
            float v = bcastf(myv, j);
            acc0 = fmaf(v, x[c + lane],      acc0);
            acc1 = fmaf(v, x[c + 64 + lane], acc1);
        }
    }

    float* yp = y + (long long)wid * DD;
    if (ACCUM) {
        yp[lane]      += acc0;
        yp[64 + lane] += acc1;
    } else {
        yp[lane]      = acc0;
        yp[64 + lane] = acc1;
    }
}

// ---------------- Dense pass: out = lrelu(x @ W^T + b) ----------------
__device__ __forceinline__ float lrelu(float x) { return x > 0.0f ? x : 0.01f * x; }

template<int MODE>
__global__ __launch_bounds__(256) void dense_pass_kernel(
    const float* __restrict__ ego,
    const float* __restrict__ side,
    const float* __restrict__ W,
    const float* __restrict__ b,
    float* __restrict__ out)
{
    __shared__ float2 Wp[128 * 64];

    const int tid = threadIdx.x;
    for (int idx = tid; idx < 128 * 64; idx += 256) {
        int l = idx >> 7;
        int k = idx & 127;
        float w0 = W[l * 128 + k];
        float w1 = W[(l + 64) * 128 + k];
        Wp[k * 64 + l] = make_float2(w0, w1);
    }
    __syncthreads();

    const int wave = tid >> 6;
    const int lane = tid & 63;

    const float bl0 = b[lane];
    const float bl1 = b[lane + 64];

    const int n_chunks = N_ENT / 32;  // 3125

    for (int chunk = blockIdx.x; chunk < n_chunks; chunk += gridDim.x) {
        const int row0 = chunk * 32 + wave * 8;

        float xs0[8], xs1[8];
#pragma unroll
        for (int r = 0; r < 8; ++r) {
            long long base = (long long)(row0 + r) * DD;
            float e0 = ego[base + lane];
            float e1 = ego[base + 64 + lane];
            float s0 = side[base + lane];
            float s1 = side[base + 64 + lane];
            if (MODE == 0) { xs0[r] = e0 + s0; xs1[r] = e1 + s1; }
            else           { xs0[r] = e0 * s0; xs1[r] = e1 * s1; }
        }

        float acc0[8], acc1[8];
#pragma unroll
        for (int r = 0; r < 8; ++r) { acc0[r] = 0.0f; acc1[r] = 0.0f; }

#pragma unroll 8
        for (int k = 0; k < 64; ++k) {
            float2 w = Wp[k * 64 + lane];
#pragma unroll
            for (int r = 0; r < 8; ++r) {
                float xk = bcastf(xs0[r], k);
                acc0[r] = fmaf(xk, w.x, acc0[r]);
                acc1[r] = fmaf(xk, w.y, acc1[r]);
            }
        }
#pragma unroll 8
        for (int k = 0; k < 64; ++k) {
            float2 w = Wp[(k + 64) * 64 + lane];
#pragma unroll
            for (int r = 0; r < 8; ++r) {
                float xk = bcastf(xs1[r], k);
                acc0[r] = fmaf(xk, w.x, acc0[r]);
                acc1[r] = fmaf(xk, w.y, acc1[r]);
            }
        }

#pragma unroll
        for (int r = 0; r < 8; ++r) {
            long long base = (long long)(row0 + r) * DD;
            float o0 = lrelu(acc0[r] + bl0);
            float o1 = lrelu(acc1[r] + bl1);
            if (MODE == 0) {
                out[base + lane]      = o0;
                out[base + 64 + lane] = o1;
            } else {
                out[base + lane]      += o0;
                out[base + 64 + lane] += o1;
            }
        }
    }
}

extern "C" void kernel_launch(void* const* d_in, const int* in_sizes, int n_in,
                              void* d_out, int out_size, void* d_ws, size_t ws_size,
                              hipStream_t stream)
{
    const float* ego     = (const float*)d_in[0];
    const int*   a_rows  = (const int*)d_in[1];
    const int*   a_cols  = (const int*)d_in[2];
    const float* a_vals  = (const float*)d_in[3];
    const int*   p1_rows = (const int*)d_in[4];
    const int*   p1_cols = (const int*)d_in[5];
    const float* p1_vals = (const float*)d_in[6];
    const int*   p2_rows = (const int*)d_in[7];
    const int*   p2_cols = (const int*)d_in[8];
    const float* p2_vals = (const float*)d_in[9];
    const int*   l1_rows = (const int*)d_in[10];
    const int*   l1_cols = (const int*)d_in[11];
    const float* l1_vals = (const float*)d_in[12];
    const int*   l2_rows = (const int*)d_in[13];
    const int*   l2_cols = (const int*)d_in[14];
    const float* l2_vals = (const float*)d_in[15];
    const float* W1      = (const float*)d_in[16];
    const float* b1      = (const float*)d_in[17];
    const float* W2      = (const float*)d_in[18];
    const float* b2      = (const float*)d_in[19];

    const int nnzA = in_sizes[1];
    const int nnzH = in_sizes[4];
    const int nnzMax = nnzA > nnzH ? nnzA : nnzH;

    // Workspace layout (element offsets, all 256B-aligned sizes)
    float* side = (float*)d_ws;                              // N_ENT*DD floats
    float* h    = side + (size_t)N_ENT * DD;                 // N_HE*DD floats
    int*   rp   = (int*)(h + (size_t)N_HE * DD);             // N_ENT+1 -> pad 100032
    int*   cnt  = rp + 100032;                               // N_ENT   -> pad 100032 (counts, then cursor)
    int*   scols = cnt + 100032;                             // nnzMax
    float* svals = (float*)(scols + nnzMax);                 // nnzMax

    auto run_spmm = [&](const int* rows, const int* cols, const float* vals,
                        int nnz, int n_rows, const float* x, float* y, bool accum) {
        hipMemsetAsync(cnt, 0, (size_t)n_rows * sizeof(int), stream);
        int hb = (nnz + 255) / 256;
        hist_kernel<<<hb, 256, 0, stream>>>(rows, cnt, nnz);
        scan_kernel<<<1, 1024, 0, stream>>>(cnt, rp, cnt, n_rows);
        scatter_kernel<<<hb, 256, 0, stream>>>(rows, cols, vals, cnt, scols, svals, nnz);
        int gb = (n_rows + 3) / 4;   // 4 waves (rows) per 256-thread block
        if (accum)
            spmm_csr_kernel<1><<<gb, 256, 0, stream>>>(rp, scols, svals, x, y, n_rows);
        else
            spmm_csr_kernel<0><<<gb, 256, 0, stream>>>(rp, scols, svals, x, y, n_rows);
    };

    // side = A_in @ ego
    run_spmm(a_rows, a_cols, a_vals, nnzA, N_ENT, ego, side, false);
    // side += p2 @ (p1 @ ego)
    run_spmm(p1_rows, p1_cols, p1_vals, nnzH, N_HE, ego, h, false);
    run_spmm(p2_rows, p2_cols, p2_vals, nnzH, N_ENT, h, side, true);
    // side += l2 @ (l1 @ ego)
    run_spmm(l1_rows, l1_cols, l1_vals, nnzH, N_HE, ego, h, false);
    run_spmm(l2_rows, l2_cols, l2_vals, nnzH, N_ENT, h, side, true);

    // out = lrelu((ego+side) @ W1^T + b1); out += lrelu((ego*side) @ W2^T + b2)
    dense_pass_kernel<0><<<1024, 256, 0, stream>>>(ego, side, W1, b1, (float*)d_out);
    dense_pass_kernel<1><<<1024, 256, 0, stream>>>(ego, side, W2, b2, (float*)d_out);
}

// Round 3
// 988.862 us; speedup vs baseline: 9.6573x; 1.6100x over previous
//
#include <hip/hip_runtime.h>

#define N_ENT 100000
#define N_HE  20000
#define DD    128

// Row-space layout for the concatenated CSR build:
#define RB_A   0
#define RB_P1  100000
#define RB_P2  120000
#define RB_L1  220000
#define RB_L2  240000
#define NROWS_TOT 340000   // total rows across all 5 matrices

__device__ __forceinline__ float bcastf(float x, int j) {
    return __int_as_float(__builtin_amdgcn_readlane(__float_as_int(x), j));
}
__device__ __forceinline__ float bf_lo(unsigned u) { return __uint_as_float(u << 16); }
__device__ __forceinline__ float bf_hi(unsigned u) { return __uint_as_float(u & 0xffff0000u); }
__device__ __forceinline__ unsigned short f2bf(float f) {
    unsigned u = __float_as_uint(f);
    unsigned r = (u + 0x7fffu + ((u >> 16) & 1u)) >> 16;   // RNE
    return (unsigned short)r;
}
__device__ __forceinline__ unsigned pack_bf16(float a, float b) {
    return (unsigned)f2bf(a) | ((unsigned)f2bf(b) << 16);
}
__device__ __forceinline__ float lrelu(float x) { return x > 0.0f ? x : 0.01f * x; }

// ---------------- fp32 -> packed bf16 pairs ----------------
__global__ __launch_bounds__(256) void convert_bf16_kernel(
    const float* __restrict__ in, unsigned* __restrict__ out2, int n2)
{
    int i = blockIdx.x * 256 + threadIdx.x;
    if (i < n2) {
        float2 v = ((const float2*)in)[i];
        out2[i] = pack_bf16(v.x, v.y);
    }
}

// ---------------- batched CSR build ----------------
struct BuildArgs {
    const int*   rows[5];
    const int*   cols[5];
    const float* vals[5];
    int nnzbase[6];   // cumulative nnz, nnzbase[5] = total
    int rowbase[5];
};

__global__ __launch_bounds__(256) void hist_all_kernel(BuildArgs a, int* __restrict__ cnt)
{
    int i = blockIdx.x * 256 + threadIdx.x;
    if (i >= a.nnzbase[5]) return;
    int seg = 0;
#pragma unroll
    for (int s = 1; s < 5; ++s) seg += (i >= a.nnzbase[s]);
    int li = i - a.nnzbase[seg];
    atomicAdd(&cnt[a.rowbase[seg] + a.rows[seg][li]], 1);
}

__global__ __launch_bounds__(256) void scatter_all_kernel(
    BuildArgs a, int* __restrict__ cursor, int2* __restrict__ cv)
{
    int i = blockIdx.x * 256 + threadIdx.x;
    if (i >= a.nnzbase[5]) return;
    int seg = 0;
#pragma unroll
    for (int s = 1; s < 5; ++s) seg += (i >= a.nnzbase[s]);
    int li = i - a.nnzbase[seg];
    int r = a.rows[seg][li];
    int c = a.cols[seg][li];
    float v = a.vals[seg][li];
    int pos = atomicAdd(&cursor[a.rowbase[seg] + r], 1);
    cv[pos] = make_int2(c * 64, __float_as_int(v));   // col pre-scaled to bf16-pair row stride
}

// ---------------- multi-block exclusive scan (3 kernels) ----------------
__global__ __launch_bounds__(256) void scan1_kernel(
    const int* __restrict__ cnt, int* __restrict__ partials, int n)
{
    __shared__ int ws[4];
    int t = threadIdx.x;
    int base = blockIdx.x * 1024 + t * 4;
    int s = 0;
#pragma unroll
    for (int j = 0; j < 4; ++j) { int i = base + j; if (i < n) s += cnt[i]; }
    for (int d = 1; d < 64; d <<= 1) s += __shfl_xor(s, d, 64);
    if ((t & 63) == 0) ws[t >> 6] = s;
    __syncthreads();
    if (t == 0) partials[blockIdx.x] = ws[0] + ws[1] + ws[2] + ws[3];
}

__global__ __launch_bounds__(512) void scan2_kernel(int* __restrict__ partials, int nb)
{
    __shared__ int tmp[512];
    int t = threadIdx.x;
    int v = (t < nb) ? partials[t] : 0;
    tmp[t] = v;
    __syncthreads();
    for (int d = 1; d < 512; d <<= 1) {
        int u = (t >= d) ? tmp[t - d] : 0;
        __syncthreads();
        tmp[t] += u;
        __syncthreads();
    }
    if (t < nb) partials[t] = tmp[t] - v;   // exclusive
}

__global__ __launch_bounds__(256) void scan3_kernel(
    const int* __restrict__ cnt, const int* __restrict__ partials,
    int* __restrict__ rp, int* __restrict__ cursor, int n)
{
    __shared__ int ws[4];
    int t = threadIdx.x, lane = t & 63, wave = t >> 6;
    int base = blockIdx.x * 1024 + t * 4;
    int v[4], p[4];
    int s = 0;
#pragma unroll
    for (int j = 0; j < 4; ++j) { int i = base + j; v[j] = (i < n) ? cnt[i] : 0; s += v[j]; p[j] = s; }
    int inc = s;
    for (int d = 1; d < 64; d <<= 1) { int u = __shfl_up(inc, d, 64); if (lane >= d) inc += u; }
    if (lane == 63) ws[wave] = inc;
    __syncthreads();
    int woff = 0;
    for (int w = 0; w < wave; ++w) woff += ws[w];
    int off = partials[blockIdx.x] + woff + (inc - s);
#pragma unroll
    for (int j = 0; j < 4; ++j) {
        int i = base + j;
        int excl = off + p[j] - v[j];
        if (i <= n) { rp[i] = excl; cursor[i] = excl; }   // i==n -> sentinel = total
    }
}

// ---------------- SpMM gather (bf16 x, fp32 accumulate) ----------------
__device__ __forceinline__ void walk_row(
    const int2* __restrict__ cv, int start, int end, int lane,
    const unsigned* __restrict__ xb, float2& acc)
{
    for (int sb = start; sb < end; sb += 64) {
        int nn = end - sb; if (nn > 64) nn = 64;
        int2 mycv = make_int2(0, 0);
        if (lane < nn) mycv = cv[sb + lane];
        int j = 0;
        for (; j + 4 <= nn; j += 4) {
            int c0 = __builtin_amdgcn_readlane(mycv.x, j);
            int c1 = __builtin_amdgcn_readlane(mycv.x, j + 1);
            int c2 = __builtin_amdgcn_readlane(mycv.x, j + 2);
            int c3 = __builtin_amdgcn_readlane(mycv.x, j + 3);
            float v0 = __int_as_float(__builtin_amdgcn_readlane(mycv.y, j));
            float v1 = __int_as_float(__builtin_amdgcn_readlane(mycv.y, j + 1));
            float v2 = __int_as_float(__builtin_amdgcn_readlane(mycv.y, j + 2));
            float v3 = __int_as_float(__builtin_amdgcn_readlane(mycv.y, j + 3));
            unsigned u0 = xb[c0 + lane];
            unsigned u1 = xb[c1 + lane];
            unsigned u2 = xb[c2 + lane];
            unsigned u3 = xb[c3 + lane];
            acc.x = fmaf(v0, bf_lo(u0), acc.x); acc.y = fmaf(v0, bf_hi(u0), acc.y);
            acc.x = fmaf(v1, bf_lo(u1), acc.x); acc.y = fmaf(v1, bf_hi(u1), acc.y);
            acc.x = fmaf(v2, bf_lo(u2), acc.x); acc.y = fmaf(v2, bf_hi(u2), acc.y);
            acc.x = fmaf(v3, bf_lo(u3), acc.x); acc.y = fmaf(v3, bf_hi(u3), acc.y);
        }
        for (; j < nn; ++j) {
            int c = __builtin_amdgcn_readlane(mycv.x, j);
            float v = __int_as_float(__builtin_amdgcn_readlane(mycv.y, j));
            unsigned u = xb[c + lane];
            acc.x = fmaf(v, bf_lo(u), acc.x);
            acc.y = fmaf(v, bf_hi(u), acc.y);
        }
    }
}

// stage 1: h1 = p1 @ ego, h2 = l1 @ ego   (outputs bf16)
__global__ __launch_bounds__(256) void spmm_stage1_kernel(
    const int* __restrict__ rp, const int2* __restrict__ cv,
    const unsigned* __restrict__ ego_bf,
    unsigned* __restrict__ h1, unsigned* __restrict__ h2)
{
    int wid = (blockIdx.x * 256 + threadIdx.x) >> 6;
    int lane = threadIdx.x & 63;
    if (wid >= 2 * N_HE) return;
    int rbase; unsigned* y;
    if (wid < N_HE) { rbase = RB_P1 + wid;           y = h1 + wid * 64; }
    else            { rbase = RB_L1 + (wid - N_HE);  y = h2 + (wid - N_HE) * 64; }
    float2 acc = make_float2(0.0f, 0.0f);
    walk_row(cv, rp[rbase], rp[rbase + 1], lane, ego_bf, acc);
    y[lane] = pack_bf16(acc.x, acc.y);
}

// stage 2: side = A@ego + p2@h1 + l2@h2   (output fp32)
__global__ __launch_bounds__(256) void spmm_stage2_kernel(
    const int* __restrict__ rp, const int2* __restrict__ cv,
    const unsigned* __restrict__ ego_bf,
    const unsigned* __restrict__ h1, const unsigned* __restrict__ h2,
    float2* __restrict__ side)
{
    int wid = (blockIdx.x * 256 + threadIdx.x) >> 6;
    int lane = threadIdx.x & 63;
    if (wid >= N_ENT) return;
    float2 acc = make_float2(0.0f, 0.0f);
    walk_row(cv, rp[RB_A  + wid], rp[RB_A  + wid + 1], lane, ego_bf, acc);
    walk_row(cv, rp[RB_P2 + wid], rp[RB_P2 + wid + 1], lane, h1, acc);
    walk_row(cv, rp[RB_L2 + wid], rp[RB_L2 + wid + 1], lane, h2, acc);
    side[wid * 64 + lane] = acc;
}

// ---------------- fused dense: out = lrelu((e+s)W1^T+b1) + lrelu((e*s)W2^T+b2) ----------------
__global__ __launch_bounds__(256) void dense_fused_kernel(
    const float* __restrict__ ego, const float* __restrict__ side,
    const float* __restrict__ W1, const float* __restrict__ b1,
    const float* __restrict__ W2, const float* __restrict__ b2,
    float* __restrict__ out)
{
    __shared__ uint2 Wp[128 * 64];   // 64 KB: {W1 pair, W2 pair} per (k, l)

    const int tid = threadIdx.x;
    for (int idx = tid; idx < 128 * 64; idx += 256) {
        int l = idx >> 7, k = idx & 127;
        unsigned q1 = pack_bf16(W1[l * 128 + k], W1[(l + 64) * 128 + k]);
        unsigned q2 = pack_bf16(W2[l * 128 + k], W2[(l + 64) * 128 + k]);
        Wp[k * 64 + l] = make_uint2(q1, q2);
    }
    __syncthreads();

    const int wave = tid >> 6, lane = tid & 63;
    const float bs0 = b1[lane], bs1 = b1[lane + 64];
    const float bb0 = b2[lane], bb1 = b2[lane + 64];

    for (int chunk = blockIdx.x; chunk < N_ENT / 32; chunk += gridDim.x) {
        const int row0 = chunk * 32 + wave * 8;

        float xs0[8], xs1[8], xb0[8], xb1[8];
#pragma unroll
        for (int r = 0; r < 8; ++r) {
            long long base = (long long)(row0 + r) * DD;
            float e0 = ego[base + lane],      e1 = ego[base + 64 + lane];
            float s0 = side[base + lane],     s1 = side[base + 64 + lane];
            xs0[r] = e0 + s0; xs1[r] = e1 + s1;
            xb0[r] = e0 * s0; xb1[r] = e1 * s1;
        }

        float aS0[8], aS1[8], aB0[8], aB1[8];
#pragma unroll
        for (int r = 0; r < 8; ++r) { aS0[r]=0; aS1[r]=0; aB0[r]=0; aB1[r]=0; }

#pragma unroll 2
        for (int k = 0; k < 64; ++k) {
            uint2 w = Wp[k * 64 + lane];
            float w1lo = bf_lo(w.x), w1hi = bf_hi(w.x);
            float w2lo = bf_lo(w.y), w2hi = bf_hi(w.y);
#pragma unroll
            for (int r = 0; r < 8; ++r) {
                float a = bcastf(xs0[r], k);
                float bq = bcastf(xb0[r], k);
                aS0[r] = fmaf(a,  w1lo, aS0[r]); aS1[r] = fmaf(a,  w1hi, aS1[r]);
                aB0[r] = fmaf(bq, w2lo, aB0[r]); aB1[r] = fmaf(bq, w2hi, aB1[r]);
            }
        }
#pragma unroll 2
        for (int k = 0; k < 64; ++k) {
            uint2 w = Wp[(k + 64) * 64 + lane];
            float w1lo = bf_lo(w.x), w1hi = bf_hi(w.x);
            float w2lo = bf_lo(w.y), w2hi = bf_hi(w.y);
#pragma unroll
            for (int r = 0; r < 8; ++r) {
                float a = bcastf(xs1[r], k);
                float bq = bcastf(xb1[r], k);
                aS0[r] = fmaf(a,  w1lo, aS0[r]); aS1[r] = fmaf(a,  w1hi, aS1[r]);
                aB0[r] = fmaf(bq, w2lo, aB0[r]); aB1[r] = fmaf(bq, w2hi, aB1[r]);
            }
        }

#pragma unroll
        for (int r = 0; r < 8; ++r) {
            long long base = (long long)(row0 + r) * DD;
            out[base + lane]      = lrelu(aS0[r] + bs0) + lrelu(aB0[r] + bb0);
            out[base + 64 + lane] = lrelu(aS1[r] + bs1) + lrelu(aB1[r] + bb1);
        }
    }
}

extern "C" void kernel_launch(void* const* d_in, const int* in_sizes, int n_in,
                              void* d_out, int out_size, void* d_ws, size_t ws_size,
                              hipStream_t stream)
{
    const float* ego  = (const float*)d_in[0];
    const float* W1   = (const float*)d_in[16];
    const float* b1   = (const float*)d_in[17];
    const float* W2   = (const float*)d_in[18];
    const float* b2   = (const float*)d_in[19];

    BuildArgs a;
    a.rows[0] = (const int*)d_in[1];  a.cols[0] = (const int*)d_in[2];  a.vals[0] = (const float*)d_in[3];
    a.rows[1] = (const int*)d_in[4];  a.cols[1] = (const int*)d_in[5];  a.vals[1] = (const float*)d_in[6];
    a.rows[2] = (const int*)d_in[7];  a.cols[2] = (const int*)d_in[8];  a.vals[2] = (const float*)d_in[9];
    a.rows[3] = (const int*)d_in[10]; a.cols[3] = (const int*)d_in[11]; a.vals[3] = (const float*)d_in[12];
    a.rows[4] = (const int*)d_in[13]; a.cols[4] = (const int*)d_in[14]; a.vals[4] = (const float*)d_in[15];
    int nnz[5] = { in_sizes[1], in_sizes[4], in_sizes[7], in_sizes[10], in_sizes[13] };
    a.nnzbase[0] = 0;
    for (int s = 0; s < 5; ++s) a.nnzbase[s + 1] = a.nnzbase[s] + nnz[s];
    a.rowbase[0] = RB_A; a.rowbase[1] = RB_P1; a.rowbase[2] = RB_P2;
    a.rowbase[3] = RB_L1; a.rowbase[4] = RB_L2;
    const int total = a.nnzbase[5];

    // ---- workspace carve (all chunks 256B-aligned) ----
    char* p = (char*)d_ws;
    float*    side    = (float*)p;        p += (size_t)N_ENT * DD * 4;     // 51.2 MB
    unsigned* ego_bf  = (unsigned*)p;     p += (size_t)N_ENT * 64 * 4;     // 25.6 MB
    unsigned* h1      = (unsigned*)p;     p += (size_t)N_HE  * 64 * 4;     // 5.12 MB
    unsigned* h2      = (unsigned*)p;     p += (size_t)N_HE  * 64 * 4;     // 5.12 MB
    int*      rp      = (int*)p;          p += 340032 * 4;                  // 1.36 MB
    int*      cnt     = (int*)p;          p += 340032 * 4;                  // 1.36 MB (also cursor)
    int*      partials= (int*)p;          p += 512 * 4;
    int2*     cv      = (int2*)p;         p += (size_t)total * 8;           // 44.8 MB

    const int NB_SCAN = (NROWS_TOT + 1023) / 1024;   // 333

    // build
    hipMemsetAsync(cnt, 0, 340032 * sizeof(int), stream);
    convert_bf16_kernel<<<(N_ENT * 64 + 255) / 256, 256, 0, stream>>>(ego, ego_bf, N_ENT * 64);
    hist_all_kernel<<<(total + 255) / 256, 256, 0, stream>>>(a, cnt);
    scan1_kernel<<<NB_SCAN, 256, 0, stream>>>(cnt, partials, NROWS_TOT);
    scan2_kernel<<<1, 512, 0, stream>>>(partials, NB_SCAN);
    scan3_kernel<<<NB_SCAN, 256, 0, stream>>>(cnt, partials, rp, cnt, NROWS_TOT);
    scatter_all_kernel<<<(total + 255) / 256, 256, 0, stream>>>(a, cnt, cv);

    // spmm
    spmm_stage1_kernel<<<(2 * N_HE) / 4, 256, 0, stream>>>(rp, cv, ego_bf, h1, h2);
    spmm_stage2_kernel<<<N_ENT / 4, 256, 0, stream>>>(rp, cv, ego_bf, h1, h2, (float2*)side);

    // dense epilogue
    dense_fused_kernel<<<1024, 256, 0, stream>>>(ego, side, W1, b1, W2, b2, (float*)d_out);
}

// Round 4
// 590.282 us; speedup vs baseline: 16.1782x; 1.6752x over previous
//
#include <hip/hip_runtime.h>

#define N_ENT 100000
#define N_HE  20000
#define DD    128

// Global row space (concatenated over the 5 matrices)
#define RB_A   0
#define RB_P1  100000
#define RB_P2  120000
#define RB_L1  220000
#define RB_L2  240000
#define NROWS_TOT 340000

// Bucket geometry: regions {A,P1,P2,L1,L2}
//   shift: {10,8,10,8,10} -> bucket strides {1024,256,1024,256,1024} rows
//   buckets: {98,79,98,79,98} -> NB=452
//   caps (entries, >=8 sigma over expected): {17408,13824,11264,13824,11264}
#define NB 452
#define TILE 6144
#define TOTAL_ARENA 6097920LL

__device__ __forceinline__ int bucket_region(int b) {
    return (b < 98) ? 0 : (b < 177) ? 1 : (b < 275) ? 2 : (b < 354) ? 3 : 4;
}
__device__ __forceinline__ int seg_shift(int s)      { return (s == 1 || s == 3) ? 8 : 10; }
__device__ __forceinline__ int seg_bucketbase(int s) { return s == 0 ? 0 : s == 1 ? 98 : s == 2 ? 177 : s == 3 ? 275 : 354; }
__device__ __forceinline__ int seg_cap(int s)        { return s == 0 ? 17408 : (s == 1 || s == 3) ? 13824 : 11264; }
__device__ __forceinline__ long long seg_arenabase(int s) {
    return s == 0 ? 0LL : s == 1 ? 1705984LL : s == 2 ? 2798080LL : s == 3 ? 3901952LL : 4994048LL;
}
__device__ __forceinline__ int seg_rowbase(int s)    { return s == 0 ? 0 : s == 1 ? 100000 : s == 2 ? 120000 : s == 3 ? 220000 : 240000; }
__device__ __forceinline__ int seg_rows(int s)       { return (s == 1 || s == 3) ? 20000 : 100000; }

__device__ __forceinline__ float bcastf(float x, int j) {
    return __int_as_float(__builtin_amdgcn_readlane(__float_as_int(x), j));
}
__device__ __forceinline__ float bf_lo(unsigned u) { return __uint_as_float(u << 16); }
__device__ __forceinline__ float bf_hi(unsigned u) { return __uint_as_float(u & 0xffff0000u); }
__device__ __forceinline__ unsigned short f2bf(float f) {
    unsigned u = __float_as_uint(f);
    unsigned r = (u + 0x7fffu + ((u >> 16) & 1u)) >> 16;   // RNE
    return (unsigned short)r;
}
__device__ __forceinline__ unsigned pack_bf16(float a, float b) {
    return (unsigned)f2bf(a) | ((unsigned)f2bf(b) << 16);
}
__device__ __forceinline__ float lrelu(float x) { return x > 0.0f ? x : 0.01f * x; }

// ---------------- fp32 -> packed bf16 pairs ----------------
__global__ __launch_bounds__(256) void convert_bf16_kernel(
    const float* __restrict__ in, unsigned* __restrict__ out2, int n2)
{
    int i = blockIdx.x * 256 + threadIdx.x;
    if (i < n2) {
        float2 v = ((const float2*)in)[i];
        out2[i] = pack_bf16(v.x, v.y);
    }
}

struct BuildArgs {
    const int*   rows[5];
    const int*   cols[5];
    const float* vals[5];
    int nnzbase[6];
};

__device__ __forceinline__ void seg_of(int i, const int* nnzbase, int& seg, int& li) {
    int s = 0;
    s += (i >= nnzbase[1]);
    s += (i >= nnzbase[2]);
    s += (i >= nnzbase[3]);
    s += (i >= nnzbase[4]);
    seg = s; li = i - nnzbase[s];
}

// ---------------- Phase A: LDS-binned partition into bucket arena ----------------
__global__ __launch_bounds__(256) void partition_kernel(
    BuildArgs a, int* __restrict__ gcursor, int2* __restrict__ arena)
{
    __shared__ int2 staging[TILE];         // 48 KB
    __shared__ int  hist[NB];
    __shared__ int  excl[NB + 1];
    __shared__ int  cursor[NB];
    __shared__ int  gbase[NB];

    const int t = threadIdx.x;
    const int tile_base = blockIdx.x * TILE;
    const int total = a.nnzbase[5];
    int tile_n = total - tile_base;
    if (tile_n > TILE) tile_n = TILE;
    if (tile_n <= 0) return;

    for (int i = t; i < NB; i += 256) hist[i] = 0;
    __syncthreads();

    // pass 1: bucket histogram (rows only)
    for (int j = t; j < tile_n; j += 256) {
        int i = tile_base + j;
        int seg, li; seg_of(i, a.nnzbase, seg, li);
        int row = a.rows[seg][li];
        int b = seg_bucketbase(seg) + (row >> seg_shift(seg));
        atomicAdd(&hist[b], 1);
    }
    __syncthreads();

    // wave 0: exclusive scan of hist -> excl
    if (t < 64) {
        int carry = 0;
        for (int base = 0; base < NB; base += 64) {
            int idx = base + t;
            int v = (idx < NB) ? hist[idx] : 0;
            int inc = v;
            for (int d = 1; d < 64; d <<= 1) {
                int u = __shfl_up(inc, d, 64);
                if (t >= d) inc += u;
            }
            if (idx < NB) excl[idx] = carry + inc - v;
            carry += __shfl(inc, 63, 64);
        }
        if (t == 0) excl[NB] = carry;   // == tile_n
    }
    __syncthreads();

    // reserve global arena ranges; init LDS cursors
    for (int b = t; b < NB; b += 256) {
        int c = hist[b];
        gbase[b] = (c > 0) ? atomicAdd(&gcursor[b], c) : 0;
        cursor[b] = excl[b];
    }
    __syncthreads();

    // pass 2: scatter entries into LDS staging grouped by bucket
    for (int j = t; j < tile_n; j += 256) {
        int i = tile_base + j;
        int seg, li; seg_of(i, a.nnzbase, seg, li);
        int row = a.rows[seg][li];
        int col = a.cols[seg][li];
        float v = a.vals[seg][li];
        int sh = seg_shift(seg);
        int b = seg_bucketbase(seg) + (row >> sh);
        int rl = row & ((1 << sh) - 1);
        int pos = atomicAdd(&cursor[b], 1);
        staging[pos] = make_int2((rl << 17) | col, __float_as_int(v));
    }
    __syncthreads();

    // flush: contiguous runs per bucket (binary search bucket of position)
    for (int p = t; p < tile_n; p += 256) {
        int lo = 0, hi = NB;
#pragma unroll
        for (int it = 0; it < 9; ++it) {     // 2^9 = 512 >= NB+1
            int mid = (lo + hi) >> 1;
            if (excl[mid] <= p) lo = mid; else hi = mid;
        }
        int b = lo;
        int reg = bucket_region(b);
        long long slot = seg_arenabase(reg) + (long long)(b - seg_bucketbase(reg)) * seg_cap(reg);
        arena[slot + gbase[b] + (p - excl[b])] = staging[p];
    }
}

// ---------------- bucket-count exclusive scan (452 values) ----------------
__global__ __launch_bounds__(512) void bucket_scan_kernel(
    const int* __restrict__ gcursor, int* __restrict__ bbase, int* __restrict__ rp)
{
    __shared__ int tmp[512];
    int t = threadIdx.x;
    int v = (t < NB) ? gcursor[t] : 0;
    tmp[t] = v;
    __syncthreads();
    for (int d = 1; d < 512; d <<= 1) {
        int u = (t >= d) ? tmp[t - d] : 0;
        __syncthreads();
        tmp[t] += u;
        __syncthreads();
    }
    if (t < NB) bbase[t] = tmp[t] - v;
    if (t == NB - 1) rp[NROWS_TOT] = tmp[t];
}

// ---------------- Phase B: per-bucket counting sort -> final cv + rp ----------------
__global__ __launch_bounds__(256) void bucket_sort_kernel(
    const int* __restrict__ gcursor, const int* __restrict__ bbase,
    const int2* __restrict__ arena, int2* __restrict__ cv, int* __restrict__ rp)
{
    __shared__ int hist[1024];
    __shared__ int excl[1024];
    __shared__ int wsum[4];

    const int b = blockIdx.x;
    const int t = threadIdx.x;
    const int reg = bucket_region(b);
    const int sh = seg_shift(reg);
    const int stride = 1 << sh;
    const int lb = b - seg_bucketbase(reg);
    const int row_base_local = lb << sh;
    int nrows = seg_rows(reg) - row_base_local;
    if (nrows > stride) nrows = stride;
    const long long slot = seg_arenabase(reg) + (long long)lb * seg_cap(reg);
    const int count = gcursor[b];
    const int fbase = bbase[b];

    for (int i = t; i < 1024; i += 256) hist[i] = 0;
    __syncthreads();

    for (int j = t; j < count; j += 256) {
        int key = arena[slot + j].x;
        atomicAdd(&hist[key >> 17], 1);
    }
    __syncthreads();

    // exclusive scan of 1024 bins (4 per thread, wave scans + cross-wave carry)
    {
        const int lane = t & 63, wave = t >> 6;
        int v[4]; int s = 0;
#pragma unroll
        for (int q = 0; q < 4; ++q) { v[q] = hist[t * 4 + q]; s += v[q]; }
        int inc = s;
        for (int d = 1; d < 64; d <<= 1) {
            int u = __shfl_up(inc, d, 64);
            if (lane >= d) inc += u;
        }
        if (lane == 63) wsum[wave] = inc;
        __syncthreads();
        int woff = 0;
        for (int w = 0; w < wave; ++w) woff += wsum[w];
        int run = woff + inc - s;
#pragma unroll
        for (int q = 0; q < 4; ++q) { excl[t * 4 + q] = run; run += v[q]; }
    }
    __syncthreads();

    // rp for this bucket's rows
    const int grow0 = seg_rowbase(reg) + row_base_local;
    for (int r = t; r < nrows; r += 256)
        rp[grow0 + r] = fbase + excl[r];
    __syncthreads();

    // scatter to final row-sorted cv (excl doubles as cursor now)
    for (int j = t; j < count; j += 256) {
        int2 e = arena[slot + j];
        int r = e.x >> 17;
        int pos = atomicAdd(&excl[r], 1);
        cv[fbase + pos] = make_int2((e.x & 0x1FFFF) << 6, e.y);
    }
}

// ---------------- SpMM gather (bf16 x, fp32 accumulate) ----------------
__device__ __forceinline__ void walk_row(
    const int2* __restrict__ cv, int start, int end, int lane,
    const unsigned* __restrict__ xb, float2& acc)
{
    for (int sb = start; sb < end; sb += 64) {
        int nn = end - sb; if (nn > 64) nn = 64;
        int2 mycv = make_int2(0, 0);
        if (lane < nn) mycv = cv[sb + lane];
        int j = 0;
#pragma unroll 2
        for (; j + 4 <= nn; j += 4) {
            int c0 = __builtin_amdgcn_readlane(mycv.x, j);
            int c1 = __builtin_amdgcn_readlane(mycv.x, j + 1);
            int c2 = __builtin_amdgcn_readlane(mycv.x, j + 2);
            int c3 = __builtin_amdgcn_readlane(mycv.x, j + 3);
            float v0 = __int_as_float(__builtin_amdgcn_readlane(mycv.y, j));
            float v1 = __int_as_float(__builtin_amdgcn_readlane(mycv.y, j + 1));
            float v2 = __int_as_float(__builtin_amdgcn_readlane(mycv.y, j + 2));
            float v3 = __int_as_float(__builtin_amdgcn_readlane(mycv.y, j + 3));
            unsigned u0 = xb[c0 + lane];
            unsigned u1 = xb[c1 + lane];
            unsigned u2 = xb[c2 + lane];
            unsigned u3 = xb[c3 + lane];
            acc.x = fmaf(v0, bf_lo(u0), acc.x); acc.y = fmaf(v0, bf_hi(u0), acc.y);
            acc.x = fmaf(v1, bf_lo(u1), acc.x); acc.y = fmaf(v1, bf_hi(u1), acc.y);
            acc.x = fmaf(v2, bf_lo(u2), acc.x); acc.y = fmaf(v2, bf_hi(u2), acc.y);
            acc.x = fmaf(v3, bf_lo(u3), acc.x); acc.y = fmaf(v3, bf_hi(u3), acc.y);
        }
        for (; j < nn; ++j) {
            int c = __builtin_amdgcn_readlane(mycv.x, j);
            float v = __int_as_float(__builtin_amdgcn_readlane(mycv.y, j));
            unsigned u = xb[c + lane];
            acc.x = fmaf(v, bf_lo(u), acc.x);
            acc.y = fmaf(v, bf_hi(u), acc.y);
        }
    }
}

// stage 1: h1 = p1 @ ego, h2 = l1 @ ego   (outputs bf16)
__global__ __launch_bounds__(256) void spmm_stage1_kernel(
    const int* __restrict__ rp, const int2* __restrict__ cv,
    const unsigned* __restrict__ ego_bf,
    unsigned* __restrict__ h1, unsigned* __restrict__ h2)
{
    int wid = (blockIdx.x * 256 + threadIdx.x) >> 6;
    int lane = threadIdx.x & 63;
    if (wid >= 2 * N_HE) return;
    int rbase; unsigned* y;
    if (wid < N_HE) { rbase = RB_P1 + wid;           y = h1 + wid * 64; }
    else            { rbase = RB_L1 + (wid - N_HE);  y = h2 + (wid - N_HE) * 64; }
    float2 acc = make_float2(0.0f, 0.0f);
    walk_row(cv, rp[rbase], rp[rbase + 1], lane, ego_bf, acc);
    y[lane] = pack_bf16(acc.x, acc.y);
}

// stage 2: side = A@ego + p2@h1 + l2@h2   (output fp32)
__global__ __launch_bounds__(256) void spmm_stage2_kernel(
    const int* __restrict__ rp, const int2* __restrict__ cv,
    const unsigned* __restrict__ ego_bf,
    const unsigned* __restrict__ h1, const unsigned* __restrict__ h2,
    float2* __restrict__ side)
{
    int wid = (blockIdx.x * 256 + threadIdx.x) >> 6;
    int lane = threadIdx.x & 63;
    if (wid >= N_ENT) return;
    float2 acc = make_float2(0.0f, 0.0f);
    walk_row(cv, rp[RB_A  + wid], rp[RB_A  + wid + 1], lane, ego_bf, acc);
    walk_row(cv, rp[RB_P2 + wid], rp[RB_P2 + wid + 1], lane, h1, acc);
    walk_row(cv, rp[RB_L2 + wid], rp[RB_L2 + wid + 1], lane, h2, acc);
    side[wid * 64 + lane] = acc;
}

// ---------------- fused dense epilogue ----------------
__global__ __launch_bounds__(256) void dense_fused_kernel(
    const float* __restrict__ ego, const float* __restrict__ side,
    const float* __restrict__ W1, const float* __restrict__ b1,
    const float* __restrict__ W2, const float* __restrict__ b2,
    float* __restrict__ out)
{
    __shared__ uint2 Wp[128 * 64];   // 64 KB

    const int tid = threadIdx.x;
    for (int idx = tid; idx < 128 * 64; idx += 256) {
        int l = idx >> 7, k = idx & 127;
        unsigned q1 = pack_bf16(W1[l * 128 + k], W1[(l + 64) * 128 + k]);
        unsigned q2 = pack_bf16(W2[l * 128 + k], W2[(l + 64) * 128 + k]);
        Wp[k * 64 + l] = make_uint2(q1, q2);
    }
    __syncthreads();

    const int wave = tid >> 6, lane = tid & 63;
    const float bs0 = b1[lane], bs1 = b1[lane + 64];
    const float bb0 = b2[lane], bb1 = b2[lane + 64];

    for (int chunk = blockIdx.x; chunk < N_ENT / 32; chunk += gridDim.x) {
        const int row0 = chunk * 32 + wave * 8;

        float xs0[8], xs1[8], xb0[8], xb1[8];
#pragma unroll
        for (int r = 0; r < 8; ++r) {
            long long base = (long long)(row0 + r) * DD;
            float e0 = ego[base + lane],  e1 = ego[base + 64 + lane];
            float s0 = side[base + lane], s1 = side[base + 64 + lane];
            xs0[r] = e0 + s0; xs1[r] = e1 + s1;
            xb0[r] = e0 * s0; xb1[r] = e1 * s1;
        }

        float aS0[8], aS1[8], aB0[8], aB1[8];
#pragma unroll
        for (int r = 0; r < 8; ++r) { aS0[r]=0; aS1[r]=0; aB0[r]=0; aB1[r]=0; }

#pragma unroll 2
        for (int k = 0; k < 64; ++k) {
            uint2 w = Wp[k * 64 + lane];
            float w1lo = bf_lo(w.x), w1hi = bf_hi(w.x);
            float w2lo = bf_lo(w.y), w2hi = bf_hi(w.y);
#pragma unroll
            for (int r = 0; r < 8; ++r) {
                float a = bcastf(xs0[r], k);
                float bq = bcastf(xb0[r], k);
                aS0[r] = fmaf(a,  w1lo, aS0[r]); aS1[r] = fmaf(a,  w1hi, aS1[r]);
                aB0[r] = fmaf(bq, w2lo, aB0[r]); aB1[r] = fmaf(bq, w2hi, aB1[r]);
            }
        }
#pragma unroll 2
        for (int k = 0; k < 64; ++k) {
            uint2 w = Wp[(k + 64) * 64 + lane];
            float w1lo = bf_lo(w.x), w1hi = bf_hi(w.x);
            float w2lo = bf_lo(w.y), w2hi = bf_hi(w.y);
#pragma unroll
            for (int r = 0; r < 8; ++r) {
                float a = bcastf(xs1[r], k);
                float bq = bcastf(xb1[r], k);
                aS0[r] = fmaf(a,  w1lo, aS0[r]); aS1[r] = fmaf(a,  w1hi, aS1[r]);
                aB0[r] = fmaf(bq, w2lo, aB0[r]); aB1[r] = fmaf(bq, w2hi, aB1[r]);
            }
        }

#pragma unroll
        for (int r = 0; r < 8; ++r) {
            long long base = (long long)(row0 + r) * DD;
            out[base + lane]      = lrelu(aS0[r] + bs0) + lrelu(aB0[r] + bb0);
            out[base + 64 + lane] = lrelu(aS1[r] + bs1) + lrelu(aB1[r] + bb1);
        }
    }
}

extern "C" void kernel_launch(void* const* d_in, const int* in_sizes, int n_in,
                              void* d_out, int out_size, void* d_ws, size_t ws_size,
                              hipStream_t stream)
{
    const float* ego = (const float*)d_in[0];
    const float* W1  = (const float*)d_in[16];
    const float* b1  = (const float*)d_in[17];
    const float* W2  = (const float*)d_in[18];
    const float* b2  = (const float*)d_in[19];

    BuildArgs a;
    a.rows[0] = (const int*)d_in[1];  a.cols[0] = (const int*)d_in[2];  a.vals[0] = (const float*)d_in[3];
    a.rows[1] = (const int*)d_in[4];  a.cols[1] = (const int*)d_in[5];  a.vals[1] = (const float*)d_in[6];
    a.rows[2] = (const int*)d_in[7];  a.cols[2] = (const int*)d_in[8];  a.vals[2] = (const float*)d_in[9];
    a.rows[3] = (const int*)d_in[10]; a.cols[3] = (const int*)d_in[11]; a.vals[3] = (const float*)d_in[12];
    a.rows[4] = (const int*)d_in[13]; a.cols[4] = (const int*)d_in[14]; a.vals[4] = (const float*)d_in[15];
    int nnz[5] = { in_sizes[1], in_sizes[4], in_sizes[7], in_sizes[10], in_sizes[13] };
    a.nnzbase[0] = 0;
    for (int s = 0; s < 5; ++s) a.nnzbase[s + 1] = a.nnzbase[s] + nnz[s];
    const int total = a.nnzbase[5];

    // ---- workspace carve (arena time-shares the side region) ----
    char* p = (char*)d_ws;
    float*    side    = (float*)p;
    int2*     arena   = (int2*)p;         p += (size_t)N_ENT * DD * 4;       // 51.2 MB (arena needs 48.8)
    unsigned* ego_bf  = (unsigned*)p;     p += (size_t)N_ENT * 64 * 4;       // 25.6 MB
    unsigned* h1      = (unsigned*)p;     p += (size_t)N_HE  * 64 * 4;       // 5.12 MB
    unsigned* h2      = (unsigned*)p;     p += (size_t)N_HE  * 64 * 4;       // 5.12 MB
    int2*     cv      = (int2*)p;         p += (size_t)total * 8;            // 44.8 MB
    int*      rp      = (int*)p;          p += 340224 * 4;                   // rp[340001]
    int*      gcursor = (int*)p;          p += 512 * 4;
    int*      bbase   = (int*)p;          p += 512 * 4;

    // build
    hipMemsetAsync(gcursor, 0, NB * sizeof(int), stream);
    convert_bf16_kernel<<<(N_ENT * 64 + 255) / 256, 256, 0, stream>>>(ego, ego_bf, N_ENT * 64);
    const int nblk_part = (total + TILE - 1) / TILE;
    partition_kernel<<<nblk_part, 256, 0, stream>>>(a, gcursor, arena);
    bucket_scan_kernel<<<1, 512, 0, stream>>>(gcursor, bbase, rp);
    bucket_sort_kernel<<<NB, 256, 0, stream>>>(gcursor, bbase, arena, cv, rp);

    // spmm (arena region is dead from here; side reuses it)
    spmm_stage1_kernel<<<(2 * N_HE) / 4, 256, 0, stream>>>(rp, cv, ego_bf, h1, h2);
    spmm_stage2_kernel<<<N_ENT / 4, 256, 0, stream>>>(rp, cv, ego_bf, h1, h2, (float2*)side);

    // dense epilogue
    dense_fused_kernel<<<1024, 256, 0, stream>>>(ego, side, W1, b1, W2, b2, (float*)d_out);
}

// Round 5
// 460.945 us; speedup vs baseline: 20.7176x; 1.2806x over previous
//
#include <hip/hip_runtime.h>

#define N_ENT 100000
#define N_HE  20000
#define DD    128

// Global row space (concatenated over the 5 matrices)
#define RB_A   0
#define RB_P1  100000
#define RB_P2  120000
#define RB_L1  220000
#define RB_L2  240000
#define NROWS_TOT 340000

// Bucket geometry: regions {A,P1,P2,L1,L2}
#define NB 452
#define TILE 6144

typedef float f32x4 __attribute__((ext_vector_type(4)));
typedef short bf16x8 __attribute__((ext_vector_type(8)));

__device__ __forceinline__ int bucket_region(int b) {
    return (b < 98) ? 0 : (b < 177) ? 1 : (b < 275) ? 2 : (b < 354) ? 3 : 4;
}
__device__ __forceinline__ int seg_shift(int s)      { return (s == 1 || s == 3) ? 8 : 10; }
__device__ __forceinline__ int seg_bucketbase(int s) { return s == 0 ? 0 : s == 1 ? 98 : s == 2 ? 177 : s == 3 ? 275 : 354; }
__device__ __forceinline__ int seg_cap(int s)        { return s == 0 ? 17408 : (s == 1 || s == 3) ? 13824 : 11264; }
__device__ __forceinline__ long long seg_arenabase(int s) {
    return s == 0 ? 0LL : s == 1 ? 1705984LL : s == 2 ? 2798080LL : s == 3 ? 3901952LL : 4994048LL;
}
__device__ __forceinline__ int seg_rowbase(int s)    { return s == 0 ? 0 : s == 1 ? 100000 : s == 2 ? 120000 : s == 3 ? 220000 : 240000; }
__device__ __forceinline__ int seg_rows(int s)       { return (s == 1 || s == 3) ? 20000 : 100000; }

__device__ __forceinline__ float bcastf(float x, int j) {
    return __int_as_float(__builtin_amdgcn_readlane(__float_as_int(x), j));
}
__device__ __forceinline__ float bf_lo(unsigned u) { return __uint_as_float(u << 16); }
__device__ __forceinline__ float bf_hi(unsigned u) { return __uint_as_float(u & 0xffff0000u); }
__device__ __forceinline__ unsigned short f2bf(float f) {
    unsigned u = __float_as_uint(f);
    unsigned r = (u + 0x7fffu + ((u >> 16) & 1u)) >> 16;   // RNE
    return (unsigned short)r;
}
__device__ __forceinline__ unsigned pack_bf16(float a, float b) {
    return (unsigned)f2bf(a) | ((unsigned)f2bf(b) << 16);
}
__device__ __forceinline__ float lrelu(float x) { return x > 0.0f ? x : 0.01f * x; }

// ---------------- fp32 -> packed bf16 pairs ----------------
__global__ __launch_bounds__(256) void convert_bf16_kernel(
    const float* __restrict__ in, unsigned* __restrict__ out2, int n2)
{
    int i = blockIdx.x * 256 + threadIdx.x;
    if (i < n2) {
        float2 v = ((const float2*)in)[i];
        out2[i] = pack_bf16(v.x, v.y);
    }
}

struct BuildArgs {
    const int*   rows[5];
    const int*   cols[5];
    const float* vals[5];
    int nnzbase[6];
};

__device__ __forceinline__ void seg_of(int i, const int* nnzbase, int& seg, int& li) {
    int s = 0;
    s += (i >= nnzbase[1]);
    s += (i >= nnzbase[2]);
    s += (i >= nnzbase[3]);
    s += (i >= nnzbase[4]);
    seg = s; li = i - nnzbase[s];
}

// ---------------- Phase A: LDS-binned partition into bucket arena ----------------
__global__ __launch_bounds__(256) void partition_kernel(
    BuildArgs a, int* __restrict__ gcursor, int2* __restrict__ arena)
{
    __shared__ int2 staging[TILE];         // 48 KB
    __shared__ int  hist[NB];
    __shared__ int  excl[NB + 1];
    __shared__ int  cursor[NB];
    __shared__ int  gbase[NB];

    const int t = threadIdx.x;
    const int tile_base = blockIdx.x * TILE;
    const int total = a.nnzbase[5];
    int tile_n = total - tile_base;
    if (tile_n > TILE) tile_n = TILE;
    if (tile_n <= 0) return;

    for (int i = t; i < NB; i += 256) hist[i] = 0;
    __syncthreads();

    for (int j = t; j < tile_n; j += 256) {
        int i = tile_base + j;
        int seg, li; seg_of(i, a.nnzbase, seg, li);
        int row = a.rows[seg][li];
        int b = seg_bucketbase(seg) + (row >> seg_shift(seg));
        atomicAdd(&hist[b], 1);
    }
    __syncthreads();

    if (t < 64) {
        int carry = 0;
        for (int base = 0; base < NB; base += 64) {
            int idx = base + t;
            int v = (idx < NB) ? hist[idx] : 0;
            int inc = v;
            for (int d = 1; d < 64; d <<= 1) {
                int u = __shfl_up(inc, d, 64);
                if (t >= d) inc += u;
            }
            if (idx < NB) excl[idx] = carry + inc - v;
            carry += __shfl(inc, 63, 64);
        }
        if (t == 0) excl[NB] = carry;
    }
    __syncthreads();

    for (int b = t; b < NB; b += 256) {
        int c = hist[b];
        gbase[b] = (c > 0) ? atomicAdd(&gcursor[b], c) : 0;
        cursor[b] = excl[b];
    }
    __syncthreads();

    for (int j = t; j < tile_n; j += 256) {
        int i = tile_base + j;
        int seg, li; seg_of(i, a.nnzbase, seg, li);
        int row = a.rows[seg][li];
        int col = a.cols[seg][li];
        float v = a.vals[seg][li];
        int sh = seg_shift(seg);
        int b = seg_bucketbase(seg) + (row >> sh);
        int rl = row & ((1 << sh) - 1);
        int pos = atomicAdd(&cursor[b], 1);
        staging[pos] = make_int2((rl << 17) | col, __float_as_int(v));
    }
    __syncthreads();

    for (int p = t; p < tile_n; p += 256) {
        int lo = 0, hi = NB;
#pragma unroll
        for (int it = 0; it < 9; ++it) {
            int mid = (lo + hi) >> 1;
            if (excl[mid] <= p) lo = mid; else hi = mid;
        }
        int b = lo;
        int reg = bucket_region(b);
        long long slot = seg_arenabase(reg) + (long long)(b - seg_bucketbase(reg)) * seg_cap(reg);
        arena[slot + gbase[b] + (p - excl[b])] = staging[p];
    }
}

// ---------------- bucket-count exclusive scan ----------------
__global__ __launch_bounds__(512) void bucket_scan_kernel(
    const int* __restrict__ gcursor, int* __restrict__ bbase, int* __restrict__ rp)
{
    __shared__ int tmp[512];
    int t = threadIdx.x;
    int v = (t < NB) ? gcursor[t] : 0;
    tmp[t] = v;
    __syncthreads();
    for (int d = 1; d < 512; d <<= 1) {
        int u = (t >= d) ? tmp[t - d] : 0;
        __syncthreads();
        tmp[t] += u;
        __syncthreads();
    }
    if (t < NB) bbase[t] = tmp[t] - v;
    if (t == NB - 1) rp[NROWS_TOT] = tmp[t];
}

// ---------------- Phase B: per-bucket counting sort -> final cv + rp ----------------
__global__ __launch_bounds__(256) void bucket_sort_kernel(
    const int* __restrict__ gcursor, const int* __restrict__ bbase,
    const int2* __restrict__ arena, int2* __restrict__ cv, int* __restrict__ rp)
{
    __shared__ int hist[1024];
    __shared__ int excl[1024];
    __shared__ int wsum[4];

    const int b = blockIdx.x;
    const int t = threadIdx.x;
    const int reg = bucket_region(b);
    const int sh = seg_shift(reg);
    const int stride = 1 << sh;
    const int lb = b - seg_bucketbase(reg);
    const int row_base_local = lb << sh;
    int nrows = seg_rows(reg) - row_base_local;
    if (nrows > stride) nrows = stride;
    const long long slot = seg_arenabase(reg) + (long long)lb * seg_cap(reg);
    const int count = gcursor[b];
    const int fbase = bbase[b];

    for (int i = t; i < 1024; i += 256) hist[i] = 0;
    __syncthreads();

    for (int j = t; j < count; j += 256) {
        int key = arena[slot + j].x;
        atomicAdd(&hist[key >> 17], 1);
    }
    __syncthreads();

    {
        const int lane = t & 63, wave = t >> 6;
        int v[4]; int s = 0;
#pragma unroll
        for (int q = 0; q < 4; ++q) { v[q] = hist[t * 4 + q]; s += v[q]; }
        int inc = s;
        for (int d = 1; d < 64; d <<= 1) {
            int u = __shfl_up(inc, d, 64);
            if (lane >= d) inc += u;
        }
        if (lane == 63) wsum[wave] = inc;
        __syncthreads();
        int woff = 0;
        for (int w = 0; w < wave; ++w) woff += wsum[w];
        int run = woff + inc - s;
#pragma unroll
        for (int q = 0; q < 4; ++q) { excl[t * 4 + q] = run; run += v[q]; }
    }
    __syncthreads();

    const int grow0 = seg_rowbase(reg) + row_base_local;
    for (int r = t; r < nrows; r += 256)
        rp[grow0 + r] = fbase + excl[r];
    __syncthreads();

    for (int j = t; j < count; j += 256) {
        int2 e = arena[slot + j];
        int r = e.x >> 17;
        int pos = atomicAdd(&excl[r], 1);
        cv[fbase + pos] = make_int2((e.x & 0x1FFFF) << 6, e.y);
    }
}

// ---------------- SpMM gather (bf16 x, fp32 accumulate) ----------------
__device__ __forceinline__ void walk_row(
    const int2* __restrict__ cv, int start, int end, int lane,
    const unsigned* __restrict__ xb, float2& acc)
{
    for (int sb = start; sb < end; sb += 64) {
        int nn = end - sb; if (nn > 64) nn = 64;
        int2 mycv = make_int2(0, 0);
        if (lane < nn) mycv = cv[sb + lane];
        int j = 0;
#pragma unroll 2
        for (; j + 4 <= nn; j += 4) {
            int c0 = __builtin_amdgcn_readlane(mycv.x, j);
            int c1 = __builtin_amdgcn_readlane(mycv.x, j + 1);
            int c2 = __builtin_amdgcn_readlane(mycv.x, j + 2);
            int c3 = __builtin_amdgcn_readlane(mycv.x, j + 3);
            float v0 = __int_as_float(__builtin_amdgcn_readlane(mycv.y, j));
            float v1 = __int_as_float(__builtin_amdgcn_readlane(mycv.y, j + 1));
            float v2 = __int_as_float(__builtin_amdgcn_readlane(mycv.y, j + 2));
            float v3 = __int_as_float(__builtin_amdgcn_readlane(mycv.y, j + 3));
            unsigned u0 = xb[c0 + lane];
            unsigned u1 = xb[c1 + lane];
            unsigned u2 = xb[c2 + lane];
            unsigned u3 = xb[c3 + lane];
            acc.x = fmaf(v0, bf_lo(u0), acc.x); acc.y = fmaf(v0, bf_hi(u0), acc.y);
            acc.x = fmaf(v1, bf_lo(u1), acc.x); acc.y = fmaf(v1, bf_hi(u1), acc.y);
            acc.x = fmaf(v2, bf_lo(u2), acc.x); acc.y = fmaf(v2, bf_hi(u2), acc.y);
            acc.x = fmaf(v3, bf_lo(u3), acc.x); acc.y = fmaf(v3, bf_hi(u3), acc.y);
        }
        for (; j < nn; ++j) {
            int c = __builtin_amdgcn_readlane(mycv.x, j);
            float v = __int_as_float(__builtin_amdgcn_readlane(mycv.y, j));
            unsigned u = xb[c + lane];
            acc.x = fmaf(v, bf_lo(u), acc.x);
            acc.y = fmaf(v, bf_hi(u), acc.y);
        }
    }
}

__global__ __launch_bounds__(256) void spmm_stage1_kernel(
    const int* __restrict__ rp, const int2* __restrict__ cv,
    const unsigned* __restrict__ ego_bf,
    unsigned* __restrict__ h1, unsigned* __restrict__ h2)
{
    int wid = (blockIdx.x * 256 + threadIdx.x) >> 6;
    int lane = threadIdx.x & 63;
    if (wid >= 2 * N_HE) return;
    int rbase; unsigned* y;
    if (wid < N_HE) { rbase = RB_P1 + wid;           y = h1 + wid * 64; }
    else            { rbase = RB_L1 + (wid - N_HE);  y = h2 + (wid - N_HE) * 64; }
    float2 acc = make_float2(0.0f, 0.0f);
    walk_row(cv, rp[rbase], rp[rbase + 1], lane, ego_bf, acc);
    y[lane] = pack_bf16(acc.x, acc.y);
}

__global__ __launch_bounds__(256) void spmm_stage2_kernel(
    const int* __restrict__ rp, const int2* __restrict__ cv,
    const unsigned* __restrict__ ego_bf,
    const unsigned* __restrict__ h1, const unsigned* __restrict__ h2,
    float2* __restrict__ side)
{
    int wid = (blockIdx.x * 256 + threadIdx.x) >> 6;
    int lane = threadIdx.x & 63;
    if (wid >= N_ENT) return;
    float2 acc = make_float2(0.0f, 0.0f);
    walk_row(cv, rp[RB_A  + wid], rp[RB_A  + wid + 1], lane, ego_bf, acc);
    walk_row(cv, rp[RB_P2 + wid], rp[RB_P2 + wid + 1], lane, h1, acc);
    walk_row(cv, rp[RB_L2 + wid], rp[RB_L2 + wid + 1], lane, h2, acc);
    side[wid * 64 + lane] = acc;
}

// ---------------- MFMA dense epilogue ----------------
// out = lrelu((ego+side) @ W1^T + b1) + lrelu((ego*side) @ W2^T + b2)
// Per wave: 32 rows (2 M-tiles of 16), all 128 cols (8 N-tiles of 16),
// K=128 in 4 steps of 32 via v_mfma_f32_16x16x32_bf16.
// W1/W2 in LDS as bf16, XOR-swizzled (byte ^= (row&7)<<4) for conflict-free
// ds_read_b128. 100000 rows = 3125 exact 32-row tiles (no tail).
union BfFrag { unsigned u[4]; bf16x8 v; };

__global__ __launch_bounds__(256) void dense_mfma_kernel(
    const float* __restrict__ ego, const float* __restrict__ side,
    const float* __restrict__ W1, const float* __restrict__ b1,
    const float* __restrict__ W2, const float* __restrict__ b2,
    float* __restrict__ out)
{
    __shared__ unsigned Wb1[8192];   // 32 KB: W1 bf16, swizzled
    __shared__ unsigned Wb2[8192];   // 32 KB: W2 bf16, swizzled

    const int tid = threadIdx.x;

    // Stage both W matrices as bf16 with XOR swizzle.
    for (int idx = tid; idx < 8192; idx += 256) {
        int row = idx >> 6, pc = idx & 63;
        unsigned pk1 = pack_bf16(W1[row * 128 + pc * 2], W1[row * 128 + pc * 2 + 1]);
        unsigned pk2 = pack_bf16(W2[row * 128 + pc * 2], W2[row * 128 + pc * 2 + 1]);
        int boff = row * 256 + ((pc * 4) ^ ((row & 7) << 4));
        *(unsigned*)((char*)Wb1 + boff) = pk1;
        *(unsigned*)((char*)Wb2 + boff) = pk2;
    }
    __syncthreads();

    const int wave = tid >> 6;
    const int lane = tid & 63;
    const int m    = lane & 15;      // row-in-tile / col-in-tile
    const int kg   = lane >> 4;      // k-group 0..3

    // biases per col-tile
    float bs[8], bb[8];
#pragma unroll
    for (int c = 0; c < 8; ++c) {
        bs[c] = b1[c * 16 + m];
        bb[c] = b2[c * 16 + m];
    }

    for (int wt = blockIdx.x * 4 + wave; wt < 3125; wt += gridDim.x * 4) {
        const int grow = wt * 32;
        const long long r0 = (long long)(grow + m) * DD;        // M-tile 0 row
        const long long r1 = (long long)(grow + 16 + m) * DD;   // M-tile 1 row

        f32x4 accS0[8], accS1[8], accB0[8], accB1[8];
#pragma unroll
        for (int c = 0; c < 8; ++c) {
            accS0[c] = (f32x4)0.0f; accS1[c] = (f32x4)0.0f;
            accB0[c] = (f32x4)0.0f; accB1[c] = (f32x4)0.0f;
        }

#pragma unroll 1
        for (int kk = 0; kk < 4; ++kk) {
            const int kb = kk * 32 + kg * 8;

            float4 e0a = *(const float4*)(ego  + r0 + kb);
            float4 e0b = *(const float4*)(ego  + r0 + kb + 4);
            float4 s0a = *(const float4*)(side + r0 + kb);
            float4 s0b = *(const float4*)(side + r0 + kb + 4);
            float4 e1a = *(const float4*)(ego  + r1 + kb);
            float4 e1b = *(const float4*)(ego  + r1 + kb + 4);
            float4 s1a = *(const float4*)(side + r1 + kb);
            float4 s1b = *(const float4*)(side + r1 + kb + 4);

            BfFrag aS0, aB0, aS1, aB1;
            aS0.u[0] = pack_bf16(e0a.x + s0a.x, e0a.y + s0a.y);
            aS0.u[1] = pack_bf16(e0a.z + s0a.z, e0a.w + s0a.w);
            aS0.u[2] = pack_bf16(e0b.x + s0b.x, e0b.y + s0b.y);
            aS0.u[3] = pack_bf16(e0b.z + s0b.z, e0b.w + s0b.w);
            aB0.u[0] = pack_bf16(e0a.x * s0a.x, e0a.y * s0a.y);
            aB0.u[1] = pack_bf16(e0a.z * s0a.z, e0a.w * s0a.w);
            aB0.u[2] = pack_bf16(e0b.x * s0b.x, e0b.y * s0b.y);
            aB0.u[3] = pack_bf16(e0b.z * s0b.z, e0b.w * s0b.w);
            aS1.u[0] = pack_bf16(e1a.x + s1a.x, e1a.y + s1a.y);
            aS1.u[1] = pack_bf16(e1a.z + s1a.z, e1a.w + s1a.w);
            aS1.u[2] = pack_bf16(e1b.x + s1b.x, e1b.y + s1b.y);
            aS1.u[3] = pack_bf16(e1b.z + s1b.z, e1b.w + s1b.w);
            aB1.u[0] = pack_bf16(e1a.x * s1a.x, e1a.y * s1a.y);
            aB1.u[1] = pack_bf16(e1a.z * s1a.z, e1a.w * s1a.w);
            aB1.u[2] = pack_bf16(e1b.x * s1b.x, e1b.y * s1b.y);
            aB1.u[3] = pack_bf16(e1b.z * s1b.z, e1b.w * s1b.w);

#pragma unroll
            for (int c = 0; c < 8; ++c) {
                int wrow = c * 16 + m;
                int boff = wrow * 256 + ((kk * 64 + (kg << 4)) ^ ((wrow & 7) << 4));
                bf16x8 w1 = *(const bf16x8*)((const char*)Wb1 + boff);
                bf16x8 w2 = *(const bf16x8*)((const char*)Wb2 + boff);
                accS0[c] = __builtin_amdgcn_mfma_f32_16x16x32_bf16(aS0.v, w1, accS0[c], 0, 0, 0);
                accS1[c] = __builtin_amdgcn_mfma_f32_16x16x32_bf16(aS1.v, w1, accS1[c], 0, 0, 0);
                accB0[c] = __builtin_amdgcn_mfma_f32_16x16x32_bf16(aB0.v, w2, accB0[c], 0, 0, 0);
                accB1[c] = __builtin_amdgcn_mfma_f32_16x16x32_bf16(aB1.v, w2, accB1[c], 0, 0, 0);
            }
        }

        // Epilogue: D mapping col=lane&15, row=(lane>>4)*4+q
#pragma unroll
        for (int c = 0; c < 8; ++c) {
#pragma unroll
            for (int q = 0; q < 4; ++q) {
                int orow = grow + kg * 4 + q;
                out[(long long)orow * DD + c * 16 + m] =
                    lrelu(accS0[c][q] + bs[c]) + lrelu(accB0[c][q] + bb[c]);
                out[(long long)(orow + 16) * DD + c * 16 + m] =
                    lrelu(accS1[c][q] + bs[c]) + lrelu(accB1[c][q] + bb[c]);
            }
        }
    }
}

extern "C" void kernel_launch(void* const* d_in, const int* in_sizes, int n_in,
                              void* d_out, int out_size, void* d_ws, size_t ws_size,
                              hipStream_t stream)
{
    const float* ego = (const float*)d_in[0];
    const float* W1  = (const float*)d_in[16];
    const float* b1  = (const float*)d_in[17];
    const float* W2  = (const float*)d_in[18];
    const float* b2  = (const float*)d_in[19];

    BuildArgs a;
    a.rows[0] = (const int*)d_in[1];  a.cols[0] = (const int*)d_in[2];  a.vals[0] = (const float*)d_in[3];
    a.rows[1] = (const int*)d_in[4];  a.cols[1] = (const int*)d_in[5];  a.vals[1] = (const float*)d_in[6];
    a.rows[2] = (const int*)d_in[7];  a.cols[2] = (const int*)d_in[8];  a.vals[2] = (const float*)d_in[9];
    a.rows[3] = (const int*)d_in[10]; a.cols[3] = (const int*)d_in[11]; a.vals[3] = (const float*)d_in[12];
    a.rows[4] = (const int*)d_in[13]; a.cols[4] = (const int*)d_in[14]; a.vals[4] = (const float*)d_in[15];
    int nnz[5] = { in_sizes[1], in_sizes[4], in_sizes[7], in_sizes[10], in_sizes[13] };
    a.nnzbase[0] = 0;
    for (int s = 0; s < 5; ++s) a.nnzbase[s + 1] = a.nnzbase[s] + nnz[s];
    const int total = a.nnzbase[5];

    // ---- workspace carve (arena time-shares the side region) ----
    char* p = (char*)d_ws;
    float*    side    = (float*)p;
    int2*     arena   = (int2*)p;         p += (size_t)N_ENT * DD * 4;       // 51.2 MB (arena needs 48.8)
    unsigned* ego_bf  = (unsigned*)p;     p += (size_t)N_ENT * 64 * 4;       // 25.6 MB
    unsigned* h1      = (unsigned*)p;     p += (size_t)N_HE  * 64 * 4;       // 5.12 MB
    unsigned* h2      = (unsigned*)p;     p += (size_t)N_HE  * 64 * 4;       // 5.12 MB
    int2*     cv      = (int2*)p;         p += (size_t)total * 8;            // 44.8 MB
    int*      rp      = (int*)p;          p += 340224 * 4;
    int*      gcursor = (int*)p;          p += 512 * 4;
    int*      bbase   = (int*)p;          p += 512 * 4;

    // build
    hipMemsetAsync(gcursor, 0, NB * sizeof(int), stream);
    convert_bf16_kernel<<<(N_ENT * 64 + 255) / 256, 256, 0, stream>>>(ego, ego_bf, N_ENT * 64);
    const int nblk_part = (total + TILE - 1) / TILE;
    partition_kernel<<<nblk_part, 256, 0, stream>>>(a, gcursor, arena);
    bucket_scan_kernel<<<1, 512, 0, stream>>>(gcursor, bbase, rp);
    bucket_sort_kernel<<<NB, 256, 0, stream>>>(gcursor, bbase, arena, cv, rp);

    // spmm (arena region is dead from here; side reuses it)
    spmm_stage1_kernel<<<(2 * N_HE) / 4, 256, 0, stream>>>(rp, cv, ego_bf, h1, h2);
    spmm_stage2_kernel<<<N_ENT / 4, 256, 0, stream>>>(rp, cv, ego_bf, h1, h2, (float2*)side);

    // dense epilogue (MFMA)
    dense_mfma_kernel<<<512, 256, 0, stream>>>(ego, side, W1, b1, W2, b2, (float*)d_out);
}

// Round 6
// 428.368 us; speedup vs baseline: 22.2932x; 1.0760x over previous
//
#include <hip/hip_runtime.h>

#define N_ENT 100000
#define N_HE  20000
#define DD    128

// Global row space (concatenated over the 5 matrices)
#define RB_A   0
#define RB_P1  100000
#define RB_P2  120000
#define RB_L1  220000
#define RB_L2  240000
#define NROWS_TOT 340000

// Bucket geometry: regions {A,P1,P2,L1,L2}
#define NB 452
#define TILE 4096

typedef float f32x4 __attribute__((ext_vector_type(4)));
typedef short bf16x8 __attribute__((ext_vector_type(8)));

__device__ __forceinline__ int bucket_region(int b) {
    return (b < 98) ? 0 : (b < 177) ? 1 : (b < 275) ? 2 : (b < 354) ? 3 : 4;
}
__device__ __forceinline__ int seg_shift(int s)      { return (s == 1 || s == 3) ? 8 : 10; }
__device__ __forceinline__ int seg_bucketbase(int s) { return s == 0 ? 0 : s == 1 ? 98 : s == 2 ? 177 : s == 3 ? 275 : 354; }
__device__ __forceinline__ int seg_cap(int s)        { return s == 0 ? 17408 : (s == 1 || s == 3) ? 13824 : 11264; }
__device__ __forceinline__ long long seg_arenabase(int s) {
    return s == 0 ? 0LL : s == 1 ? 1705984LL : s == 2 ? 2798080LL : s == 3 ? 3901952LL : 4994048LL;
}
__device__ __forceinline__ int seg_rowbase(int s)    { return s == 0 ? 0 : s == 1 ? 100000 : s == 2 ? 120000 : s == 3 ? 220000 : 240000; }
__device__ __forceinline__ int seg_rows(int s)       { return (s == 1 || s == 3) ? 20000 : 100000; }

__device__ __forceinline__ float bcastf(float x, int j) {
    return __int_as_float(__builtin_amdgcn_readlane(__float_as_int(x), j));
}
__device__ __forceinline__ float bf_lo(unsigned u) { return __uint_as_float(u << 16); }
__device__ __forceinline__ float bf_hi(unsigned u) { return __uint_as_float(u & 0xffff0000u); }
__device__ __forceinline__ unsigned short f2bf(float f) {
    unsigned u = __float_as_uint(f);
    unsigned r = (u + 0x7fffu + ((u >> 16) & 1u)) >> 16;   // RNE
    return (unsigned short)r;
}
__device__ __forceinline__ unsigned pack_bf16(float a, float b) {
    return (unsigned)f2bf(a) | ((unsigned)f2bf(b) << 16);
}
__device__ __forceinline__ float lrelu(float x) { return x > 0.0f ? x : 0.01f * x; }

// ---------------- fp32 -> packed bf16 pairs ----------------
__global__ __launch_bounds__(256) void convert_bf16_kernel(
    const float* __restrict__ in, unsigned* __restrict__ out2, int n2)
{
    int i = blockIdx.x * 256 + threadIdx.x;
    if (i < n2) {
        float2 v = ((const float2*)in)[i];
        out2[i] = pack_bf16(v.x, v.y);
    }
}

struct BuildArgs {
    const int*   rows[5];
    const int*   cols[5];
    const float* vals[5];
    int nnzbase[6];
};

__device__ __forceinline__ void seg_of(int i, const int* nnzbase, int& seg, int& li) {
    int s = 0;
    s += (i >= nnzbase[1]);
    s += (i >= nnzbase[2]);
    s += (i >= nnzbase[3]);
    s += (i >= nnzbase[4]);
    seg = s; li = i - nnzbase[s];
}

// ---------------- Phase A: LDS-binned partition into bucket arena ----------------
// TILE=4096 (16 entries/thread), LDS ~39 KB -> 4 blocks/CU.
__global__ __launch_bounds__(256, 4) void partition_kernel(
    BuildArgs a, int* __restrict__ gcursor, int2* __restrict__ arena)
{
    __shared__ int2 staging[TILE];         // 32 KB
    __shared__ int  hist[NB];
    __shared__ int  excl[NB + 1];
    __shared__ int  cursor[NB];
    __shared__ int  gbase[NB];

    const int t = threadIdx.x;
    const int tile_base = blockIdx.x * TILE;
    const int total = a.nnzbase[5];
    int tile_n = total - tile_base;
    if (tile_n > TILE) tile_n = TILE;
    if (tile_n <= 0) return;

    for (int i = t; i < NB; i += 256) hist[i] = 0;
    __syncthreads();

    // pass A: read rows once, histogram, cache (bucket<<10 | row_local) in regs
    int pk[16];
#pragma unroll
    for (int q = 0; q < 16; ++q) {
        int j = t + q * 256;
        pk[q] = -1;
        if (j < tile_n) {
            int i = tile_base + j;
            int seg, li; seg_of(i, a.nnzbase, seg, li);
            int row = a.rows[seg][li];
            int sh = seg_shift(seg);
            int b = seg_bucketbase(seg) + (row >> sh);
            int rl = row & ((1 << sh) - 1);
            pk[q] = (b << 10) | rl;
            atomicAdd(&hist[b], 1);
        }
    }
    __syncthreads();

    // wave 0: exclusive scan of hist -> excl
    if (t < 64) {
        int carry = 0;
        for (int base = 0; base < NB; base += 64) {
            int idx = base + t;
            int v = (idx < NB) ? hist[idx] : 0;
            int inc = v;
            for (int d = 1; d < 64; d <<= 1) {
                int u = __shfl_up(inc, d, 64);
                if (t >= d) inc += u;
            }
            if (idx < NB) excl[idx] = carry + inc - v;
            carry += __shfl(inc, 63, 64);
        }
        if (t == 0) excl[NB] = carry;
    }
    __syncthreads();

    // reserve global arena ranges; init LDS cursors
    for (int b = t; b < NB; b += 256) {
        int c = hist[b];
        gbase[b] = (c > 0) ? atomicAdd(&gcursor[b], c) : 0;
        cursor[b] = excl[b];
    }
    __syncthreads();

    // pass B: read cols/vals, scatter into LDS staging grouped by bucket
#pragma unroll
    for (int q = 0; q < 16; ++q) {
        int j = t + q * 256;
        if (j < tile_n) {
            int i = tile_base + j;
            int seg, li; seg_of(i, a.nnzbase, seg, li);
            int col = a.cols[seg][li];
            float v = a.vals[seg][li];
            int b = pk[q] >> 10;
            int rl = pk[q] & 1023;
            int pos = atomicAdd(&cursor[b], 1);
            staging[pos] = make_int2((rl << 17) | col, __float_as_int(v));
        }
    }
    __syncthreads();

    // flush: contiguous runs per bucket (binary search bucket of position)
    for (int p = t; p < tile_n; p += 256) {
        int lo = 0, hi = NB;
#pragma unroll
        for (int it = 0; it < 9; ++it) {
            int mid = (lo + hi) >> 1;
            if (excl[mid] <= p) lo = mid; else hi = mid;
        }
        int b = lo;
        int reg = bucket_region(b);
        long long slot = seg_arenabase(reg) + (long long)(b - seg_bucketbase(reg)) * seg_cap(reg);
        arena[slot + gbase[b] + (p - excl[b])] = staging[p];
    }
}

// ---------------- bucket-count exclusive scan ----------------
__global__ __launch_bounds__(512) void bucket_scan_kernel(
    const int* __restrict__ gcursor, int* __restrict__ bbase, int* __restrict__ rp)
{
    __shared__ int tmp[512];
    int t = threadIdx.x;
    int v = (t < NB) ? gcursor[t] : 0;
    tmp[t] = v;
    __syncthreads();
    for (int d = 1; d < 512; d <<= 1) {
        int u = (t >= d) ? tmp[t - d] : 0;
        __syncthreads();
        tmp[t] += u;
        __syncthreads();
    }
    if (t < NB) bbase[t] = tmp[t] - v;
    if (t == NB - 1) rp[NROWS_TOT] = tmp[t];
}

// ---------------- Phase B: per-bucket counting sort -> final cv + rp ----------------
__global__ __launch_bounds__(256) void bucket_sort_kernel(
    const int* __restrict__ gcursor, const int* __restrict__ bbase,
    const int2* __restrict__ arena, int2* __restrict__ cv, int* __restrict__ rp)
{
    __shared__ int hist[1024];
    __shared__ int excl[1024];
    __shared__ int wsum[4];

    const int b = blockIdx.x;
    const int t = threadIdx.x;
    const int reg = bucket_region(b);
    const int sh = seg_shift(reg);
    const int stride = 1 << sh;
    const int lb = b - seg_bucketbase(reg);
    const int row_base_local = lb << sh;
    int nrows = seg_rows(reg) - row_base_local;
    if (nrows > stride) nrows = stride;
    const long long slot = seg_arenabase(reg) + (long long)lb * seg_cap(reg);
    const int count = gcursor[b];
    const int fbase = bbase[b];

    for (int i = t; i < 1024; i += 256) hist[i] = 0;
    __syncthreads();

    for (int j = t; j < count; j += 256) {
        int key = arena[slot + j].x;
        atomicAdd(&hist[key >> 17], 1);
    }
    __syncthreads();

    {
        const int lane = t & 63, wave = t >> 6;
        int v[4]; int s = 0;
#pragma unroll
        for (int q = 0; q < 4; ++q) { v[q] = hist[t * 4 + q]; s += v[q]; }
        int inc = s;
        for (int d = 1; d < 64; d <<= 1) {
            int u = __shfl_up(inc, d, 64);
            if (lane >= d) inc += u;
        }
        if (lane == 63) wsum[wave] = inc;
        __syncthreads();
        int woff = 0;
        for (int w = 0; w < wave; ++w) woff += wsum[w];
        int run = woff + inc - s;
#pragma unroll
        for (int q = 0; q < 4; ++q) { excl[t * 4 + q] = run; run += v[q]; }
    }
    __syncthreads();

    const int grow0 = seg_rowbase(reg) + row_base_local;
    for (int r = t; r < nrows; r += 256)
        rp[grow0 + r] = fbase + excl[r];
    __syncthreads();

    for (int j = t; j < count; j += 256) {
        int2 e = arena[slot + j];
        int r = e.x >> 17;
        int pos = atomicAdd(&excl[r], 1);
        cv[fbase + pos] = make_int2((e.x & 0x1FFFF) << 6, e.y);
    }
}

// ---------------- SpMM gather (bf16 x, fp32 accumulate) ----------------
__device__ __forceinline__ void walk_row(
    const int2* __restrict__ cv, int start, int end, int lane,
    const unsigned* __restrict__ xb, float2& acc)
{
    for (int sb = start; sb < end; sb += 64) {
        int nn = end - sb; if (nn > 64) nn = 64;
        int2 mycv = make_int2(0, 0);
        if (lane < nn) mycv = cv[sb + lane];
        int j = 0;
#pragma unroll 2
        for (; j + 4 <= nn; j += 4) {
            int c0 = __builtin_amdgcn_readlane(mycv.x, j);
            int c1 = __builtin_amdgcn_readlane(mycv.x, j + 1);
            int c2 = __builtin_amdgcn_readlane(mycv.x, j + 2);
            int c3 = __builtin_amdgcn_readlane(mycv.x, j + 3);
            float v0 = __int_as_float(__builtin_amdgcn_readlane(mycv.y, j));
            float v1 = __int_as_float(__builtin_amdgcn_readlane(mycv.y, j + 1));
            float v2 = __int_as_float(__builtin_amdgcn_readlane(mycv.y, j + 2));
            float v3 = __int_as_float(__builtin_amdgcn_readlane(mycv.y, j + 3));
            unsigned u0 = xb[c0 + lane];
            unsigned u1 = xb[c1 + lane];
            unsigned u2 = xb[c2 + lane];
            unsigned u3 = xb[c3 + lane];
            acc.x = fmaf(v0, bf_lo(u0), acc.x); acc.y = fmaf(v0, bf_hi(u0), acc.y);
            acc.x = fmaf(v1, bf_lo(u1), acc.x); acc.y = fmaf(v1, bf_hi(u1), acc.y);
            acc.x = fmaf(v2, bf_lo(u2), acc.x); acc.y = fmaf(v2, bf_hi(u2), acc.y);
            acc.x = fmaf(v3, bf_lo(u3), acc.x); acc.y = fmaf(v3, bf_hi(u3), acc.y);
        }
        for (; j < nn; ++j) {
            int c = __builtin_amdgcn_readlane(mycv.x, j);
            float v = __int_as_float(__builtin_amdgcn_readlane(mycv.y, j));
            unsigned u = xb[c + lane];
            acc.x = fmaf(v, bf_lo(u), acc.x);
            acc.y = fmaf(v, bf_hi(u), acc.y);
        }
    }
}

__global__ __launch_bounds__(256) void spmm_stage1_kernel(
    const int* __restrict__ rp, const int2* __restrict__ cv,
    const unsigned* __restrict__ ego_bf,
    unsigned* __restrict__ h1, unsigned* __restrict__ h2)
{
    int wid = (blockIdx.x * 256 + threadIdx.x) >> 6;
    int lane = threadIdx.x & 63;
    if (wid >= 2 * N_HE) return;
    int rbase; unsigned* y;
    if (wid < N_HE) { rbase = RB_P1 + wid;           y = h1 + wid * 64; }
    else            { rbase = RB_L1 + (wid - N_HE);  y = h2 + (wid - N_HE) * 64; }
    float2 acc = make_float2(0.0f, 0.0f);
    walk_row(cv, rp[rbase], rp[rbase + 1], lane, ego_bf, acc);
    y[lane] = pack_bf16(acc.x, acc.y);
}

__global__ __launch_bounds__(256) void spmm_stage2_kernel(
    const int* __restrict__ rp, const int2* __restrict__ cv,
    const unsigned* __restrict__ ego_bf,
    const unsigned* __restrict__ h1, const unsigned* __restrict__ h2,
    float2* __restrict__ side)
{
    int wid = (blockIdx.x * 256 + threadIdx.x) >> 6;
    int lane = threadIdx.x & 63;
    if (wid >= N_ENT) return;
    float2 acc = make_float2(0.0f, 0.0f);
    walk_row(cv, rp[RB_A  + wid], rp[RB_A  + wid + 1], lane, ego_bf, acc);
    walk_row(cv, rp[RB_P2 + wid], rp[RB_P2 + wid + 1], lane, h1, acc);
    walk_row(cv, rp[RB_L2 + wid], rp[RB_L2 + wid + 1], lane, h2, acc);
    side[wid * 64 + lane] = acc;
}

// ---------------- MFMA dense epilogue ----------------
union BfFrag { unsigned u[4]; bf16x8 v; };

__global__ __launch_bounds__(256) void dense_mfma_kernel(
    const float* __restrict__ ego, const float* __restrict__ side,
    const float* __restrict__ W1, const float* __restrict__ b1,
    const float* __restrict__ W2, const float* __restrict__ b2,
    float* __restrict__ out)
{
    __shared__ unsigned Wb1[8192];   // 32 KB: W1 bf16, swizzled
    __shared__ unsigned Wb2[8192];   // 32 KB: W2 bf16, swizzled

    const int tid = threadIdx.x;

    for (int idx = tid; idx < 8192; idx += 256) {
        int row = idx >> 6, pc = idx & 63;
        unsigned pk1 = pack_bf16(W1[row * 128 + pc * 2], W1[row * 128 + pc * 2 + 1]);
        unsigned pk2 = pack_bf16(W2[row * 128 + pc * 2], W2[row * 128 + pc * 2 + 1]);
        int boff = row * 256 + ((pc * 4) ^ ((row & 7) << 4));
        *(unsigned*)((char*)Wb1 + boff) = pk1;
        *(unsigned*)((char*)Wb2 + boff) = pk2;
    }
    __syncthreads();

    const int wave = tid >> 6;
    const int lane = tid & 63;
    const int m    = lane & 15;
    const int kg   = lane >> 4;

    float bs[8], bb[8];
#pragma unroll
    for (int c = 0; c < 8; ++c) {
        bs[c] = b1[c * 16 + m];
        bb[c] = b2[c * 16 + m];
    }

    for (int wt = blockIdx.x * 4 + wave; wt < 3125; wt += gridDim.x * 4) {
        const int grow = wt * 32;
        const long long r0 = (long long)(grow + m) * DD;
        const long long r1 = (long long)(grow + 16 + m) * DD;

        f32x4 accS0[8], accS1[8], accB0[8], accB1[8];
#pragma unroll
        for (int c = 0; c < 8; ++c) {
            accS0[c] = (f32x4)0.0f; accS1[c] = (f32x4)0.0f;
            accB0[c] = (f32x4)0.0f; accB1[c] = (f32x4)0.0f;
        }

#pragma unroll 1
        for (int kk = 0; kk < 4; ++kk) {
            const int kb = kk * 32 + kg * 8;

            float4 e0a = *(const float4*)(ego  + r0 + kb);
            float4 e0b = *(const float4*)(ego  + r0 + kb + 4);
            float4 s0a = *(const float4*)(side + r0 + kb);
            float4 s0b = *(const float4*)(side + r0 + kb + 4);
            float4 e1a = *(const float4*)(ego  + r1 + kb);
            float4 e1b = *(const float4*)(ego  + r1 + kb + 4);
            float4 s1a = *(const float4*)(side + r1 + kb);
            float4 s1b = *(const float4*)(side + r1 + kb + 4);

            BfFrag aS0, aB0, aS1, aB1;
            aS0.u[0] = pack_bf16(e0a.x + s0a.x, e0a.y + s0a.y);
            aS0.u[1] = pack_bf16(e0a.z + s0a.z, e0a.w + s0a.w);
            aS0.u[2] = pack_bf16(e0b.x + s0b.x, e0b.y + s0b.y);
            aS0.u[3] = pack_bf16(e0b.z + s0b.z, e0b.w + s0b.w);
            aB0.u[0] = pack_bf16(e0a.x * s0a.x, e0a.y * s0a.y);
            aB0.u[1] = pack_bf16(e0a.z * s0a.z, e0a.w * s0a.w);
            aB0.u[2] = pack_bf16(e0b.x * s0b.x, e0b.y * s0b.y);
            aB0.u[3] = pack_bf16(e0b.z * s0b.z, e0b.w * s0b.w);
            aS1.u[0] = pack_bf16(e1a.x + s1a.x, e1a.y + s1a.y);
            aS1.u[1] = pack_bf16(e1a.z + s1a.z, e1a.w + s1a.w);
            aS1.u[2] = pack_bf16(e1b.x + s1b.x, e1b.y + s1b.y);
            aS1.u[3] = pack_bf16(e1b.z + s1b.z, e1b.w + s1b.w);
            aB1.u[0] = pack_bf16(e1a.x * s1a.x, e1a.y * s1a.y);
            aB1.u[1] = pack_bf16(e1a.z * s1a.z, e1a.w * s1a.w);
            aB1.u[2] = pack_bf16(e1b.x * s1b.x, e1b.y * s1b.y);
            aB1.u[3] = pack_bf16(e1b.z * s1b.z, e1b.w * s1b.w);

#pragma unroll
            for (int c = 0; c < 8; ++c) {
                int wrow = c * 16 + m;
                int boff = wrow * 256 + ((kk * 64 + (kg << 4)) ^ ((wrow & 7) << 4));
                bf16x8 w1 = *(const bf16x8*)((const char*)Wb1 + boff);
                bf16x8 w2 = *(const bf16x8*)((const char*)Wb2 + boff);
                accS0[c] = __builtin_amdgcn_mfma_f32_16x16x32_bf16(aS0.v, w1, accS0[c], 0, 0, 0);
                accS1[c] = __builtin_amdgcn_mfma_f32_16x16x32_bf16(aS1.v, w1, accS1[c], 0, 0, 0);
                accB0[c] = __builtin_amdgcn_mfma_f32_16x16x32_bf16(aB0.v, w2, accB0[c], 0, 0, 0);
                accB1[c] = __builtin_amdgcn_mfma_f32_16x16x32_bf16(aB1.v, w2, accB1[c], 0, 0, 0);
            }
        }

#pragma unroll
        for (int c = 0; c < 8; ++c) {
#pragma unroll
            for (int q = 0; q < 4; ++q) {
                int orow = grow + kg * 4 + q;
                out[(long long)orow * DD + c * 16 + m] =
                    lrelu(accS0[c][q] + bs[c]) + lrelu(accB0[c][q] + bb[c]);
                out[(long long)(orow + 16) * DD + c * 16 + m] =
                    lrelu(accS1[c][q] + bs[c]) + lrelu(accB1[c][q] + bb[c]);
            }
        }
    }
}

extern "C" void kernel_launch(void* const* d_in, const int* in_sizes, int n_in,
                              void* d_out, int out_size, void* d_ws, size_t ws_size,
                              hipStream_t stream)
{
    const float* ego = (const float*)d_in[0];
    const float* W1  = (const float*)d_in[16];
    const float* b1  = (const float*)d_in[17];
    const float* W2  = (const float*)d_in[18];
    const float* b2  = (const float*)d_in[19];

    BuildArgs a;
    a.rows[0] = (const int*)d_in[1];  a.cols[0] = (const int*)d_in[2];  a.vals[0] = (const float*)d_in[3];
    a.rows[1] = (const int*)d_in[4];  a.cols[1] = (const int*)d_in[5];  a.vals[1] = (const float*)d_in[6];
    a.rows[2] = (const int*)d_in[7];  a.cols[2] = (const int*)d_in[8];  a.vals[2] = (const float*)d_in[9];
    a.rows[3] = (const int*)d_in[10]; a.cols[3] = (const int*)d_in[11]; a.vals[3] = (const float*)d_in[12];
    a.rows[4] = (const int*)d_in[13]; a.cols[4] = (const int*)d_in[14]; a.vals[4] = (const float*)d_in[15];
    int nnz[5] = { in_sizes[1], in_sizes[4], in_sizes[7], in_sizes[10], in_sizes[13] };
    a.nnzbase[0] = 0;
    for (int s = 0; s < 5; ++s) a.nnzbase[s + 1] = a.nnzbase[s] + nnz[s];
    const int total = a.nnzbase[5];

    // ---- workspace carve (arena time-shares the side region) ----
    char* p = (char*)d_ws;
    float*    side    = (float*)p;
    int2*     arena   = (int2*)p;         p += (size_t)N_ENT * DD * 4;       // 51.2 MB (arena needs 48.8)
    unsigned* ego_bf  = (unsigned*)p;     p += (size_t)N_ENT * 64 * 4;       // 25.6 MB
    unsigned* h1      = (unsigned*)p;     p += (size_t)N_HE  * 64 * 4;       // 5.12 MB
    unsigned* h2      = (unsigned*)p;     p += (size_t)N_HE  * 64 * 4;       // 5.12 MB
    int2*     cv      = (int2*)p;         p += (size_t)total * 8;            // 44.8 MB
    int*      rp      = (int*)p;          p += 340224 * 4;
    int*      gcursor = (int*)p;          p += 512 * 4;
    int*      bbase   = (int*)p;          p += 512 * 4;

    // build
    hipMemsetAsync(gcursor, 0, NB * sizeof(int), stream);
    convert_bf16_kernel<<<(N_ENT * 64 + 255) / 256, 256, 0, stream>>>(ego, ego_bf, N_ENT * 64);
    const int nblk_part = (total + TILE - 1) / TILE;
    partition_kernel<<<nblk_part, 256, 0, stream>>>(a, gcursor, arena);
    bucket_scan_kernel<<<1, 512, 0, stream>>>(gcursor, bbase, rp);
    bucket_sort_kernel<<<NB, 256, 0, stream>>>(gcursor, bbase, arena, cv, rp);

    // spmm (arena region is dead from here; side reuses it)
    spmm_stage1_kernel<<<(2 * N_HE) / 4, 256, 0, stream>>>(rp, cv, ego_bf, h1, h2);
    spmm_stage2_kernel<<<N_ENT / 4, 256, 0, stream>>>(rp, cv, ego_bf, h1, h2, (float2*)side);

    // dense epilogue (MFMA)
    dense_mfma_kernel<<<512, 256, 0, stream>>>(ego, side, W1, b1, W2, b2, (float*)d_out);
}

// Round 7
// 425.642 us; speedup vs baseline: 22.4360x; 1.0064x over previous
//
#include <hip/hip_runtime.h>

#define N_ENT 100000
#define N_HE  20000
#define DD    128

// Global row space (concatenated over the 5 matrices)
#define RB_A   0
#define RB_P1  100000
#define RB_P2  120000
#define RB_L1  220000
#define RB_L2  240000
#define NROWS_TOT 340000

// Bucket geometry: regions {A,P1,P2,L1,L2}
#define NB 452
#define TILE 4096

typedef float f32x4 __attribute__((ext_vector_type(4)));
typedef short bf16x8 __attribute__((ext_vector_type(8)));

__device__ __forceinline__ int bucket_region(int b) {
    return (b < 98) ? 0 : (b < 177) ? 1 : (b < 275) ? 2 : (b < 354) ? 3 : 4;
}
__device__ __forceinline__ int seg_shift(int s)      { return (s == 1 || s == 3) ? 8 : 10; }
__device__ __forceinline__ int seg_bucketbase(int s) { return s == 0 ? 0 : s == 1 ? 98 : s == 2 ? 177 : s == 3 ? 275 : 354; }
__device__ __forceinline__ int seg_cap(int s)        { return s == 0 ? 17408 : (s == 1 || s == 3) ? 13824 : 11264; }
__device__ __forceinline__ long long seg_arenabase(int s) {
    return s == 0 ? 0LL : s == 1 ? 1705984LL : s == 2 ? 2798080LL : s == 3 ? 3901952LL : 4994048LL;
}
__device__ __forceinline__ int seg_rowbase(int s)    { return s == 0 ? 0 : s == 1 ? 100000 : s == 2 ? 120000 : s == 3 ? 220000 : 240000; }
__device__ __forceinline__ int seg_rows(int s)       { return (s == 1 || s == 3) ? 20000 : 100000; }

__device__ __forceinline__ float bf_lo(unsigned u) { return __uint_as_float(u << 16); }
__device__ __forceinline__ float bf_hi(unsigned u) { return __uint_as_float(u & 0xffff0000u); }
__device__ __forceinline__ unsigned short f2bf(float f) {
    unsigned u = __float_as_uint(f);
    unsigned r = (u + 0x7fffu + ((u >> 16) & 1u)) >> 16;   // RNE
    return (unsigned short)r;
}
__device__ __forceinline__ unsigned pack_bf16(float a, float b) {
    return (unsigned)f2bf(a) | ((unsigned)f2bf(b) << 16);
}
__device__ __forceinline__ float lrelu(float x) { return x > 0.0f ? x : 0.01f * x; }

// ---------------- fp32 -> packed bf16 pairs ----------------
__global__ __launch_bounds__(256) void convert_bf16_kernel(
    const float* __restrict__ in, unsigned* __restrict__ out2, int n2)
{
    int i = blockIdx.x * 256 + threadIdx.x;
    if (i < n2) {
        float2 v = ((const float2*)in)[i];
        out2[i] = pack_bf16(v.x, v.y);
    }
}

struct BuildArgs {
    const int*   rows[5];
    const int*   cols[5];
    const float* vals[5];
    int nnzbase[6];
};

__device__ __forceinline__ void seg_of(int i, const int* nnzbase, int& seg, int& li) {
    int s = 0;
    s += (i >= nnzbase[1]);
    s += (i >= nnzbase[2]);
    s += (i >= nnzbase[3]);
    s += (i >= nnzbase[4]);
    seg = s; li = i - nnzbase[s];
}

// ---------------- Phase A: LDS-binned partition into bucket arena ----------------
__global__ __launch_bounds__(256, 4) void partition_kernel(
    BuildArgs a, int* __restrict__ gcursor, int2* __restrict__ arena)
{
    __shared__ int2 staging[TILE];         // 32 KB
    __shared__ int  hist[NB];
    __shared__ int  excl[NB + 1];
    __shared__ int  cursor[NB];
    __shared__ int  gbase[NB];

    const int t = threadIdx.x;
    const int tile_base = blockIdx.x * TILE;
    const int total = a.nnzbase[5];
    int tile_n = total - tile_base;
    if (tile_n > TILE) tile_n = TILE;
    if (tile_n <= 0) return;

    for (int i = t; i < NB; i += 256) hist[i] = 0;
    __syncthreads();

    int pk[16];
#pragma unroll
    for (int q = 0; q < 16; ++q) {
        int j = t + q * 256;
        pk[q] = -1;
        if (j < tile_n) {
            int i = tile_base + j;
            int seg, li; seg_of(i, a.nnzbase, seg, li);
            int row = a.rows[seg][li];
            int sh = seg_shift(seg);
            int b = seg_bucketbase(seg) + (row >> sh);
            int rl = row & ((1 << sh) - 1);
            pk[q] = (b << 10) | rl;
            atomicAdd(&hist[b], 1);
        }
    }
    __syncthreads();

    if (t < 64) {
        int carry = 0;
        for (int base = 0; base < NB; base += 64) {
            int idx = base + t;
            int v = (idx < NB) ? hist[idx] : 0;
            int inc = v;
            for (int d = 1; d < 64; d <<= 1) {
                int u = __shfl_up(inc, d, 64);
                if (t >= d) inc += u;
            }
            if (idx < NB) excl[idx] = carry + inc - v;
            carry += __shfl(inc, 63, 64);
        }
        if (t == 0) excl[NB] = carry;
    }
    __syncthreads();

    for (int b = t; b < NB; b += 256) {
        int c = hist[b];
        gbase[b] = (c > 0) ? atomicAdd(&gcursor[b], c) : 0;
        cursor[b] = excl[b];
    }
    __syncthreads();

#pragma unroll
    for (int q = 0; q < 16; ++q) {
        int j = t + q * 256;
        if (j < tile_n) {
            int i = tile_base + j;
            int seg, li; seg_of(i, a.nnzbase, seg, li);
            int col = a.cols[seg][li];
            float v = a.vals[seg][li];
            int b = pk[q] >> 10;
            int rl = pk[q] & 1023;
            int pos = atomicAdd(&cursor[b], 1);
            staging[pos] = make_int2((rl << 17) | col, __float_as_int(v));
        }
    }
    __syncthreads();

    for (int p = t; p < tile_n; p += 256) {
        int lo = 0, hi = NB;
#pragma unroll
        for (int it = 0; it < 9; ++it) {
            int mid = (lo + hi) >> 1;
            if (excl[mid] <= p) lo = mid; else hi = mid;
        }
        int b = lo;
        int reg = bucket_region(b);
        long long slot = seg_arenabase(reg) + (long long)(b - seg_bucketbase(reg)) * seg_cap(reg);
        arena[slot + gbase[b] + (p - excl[b])] = staging[p];
    }
}

// ---------------- bucket-count exclusive scan ----------------
__global__ __launch_bounds__(512) void bucket_scan_kernel(
    const int* __restrict__ gcursor, int* __restrict__ bbase, int* __restrict__ rp)
{
    __shared__ int tmp[512];
    int t = threadIdx.x;
    int v = (t < NB) ? gcursor[t] : 0;
    tmp[t] = v;
    __syncthreads();
    for (int d = 1; d < 512; d <<= 1) {
        int u = (t >= d) ? tmp[t - d] : 0;
        __syncthreads();
        tmp[t] += u;
        __syncthreads();
    }
    if (t < NB) bbase[t] = tmp[t] - v;
    if (t == NB - 1) rp[NROWS_TOT] = tmp[t];
}

// ---------------- Phase B: per-bucket counting sort -> final cv + rp ----------------
__global__ __launch_bounds__(256) void bucket_sort_kernel(
    const int* __restrict__ gcursor, const int* __restrict__ bbase,
    const int2* __restrict__ arena, int2* __restrict__ cv, int* __restrict__ rp)
{
    __shared__ int hist[1024];
    __shared__ int excl[1024];
    __shared__ int wsum[4];

    const int b = blockIdx.x;
    const int t = threadIdx.x;
    const int reg = bucket_region(b);
    const int sh = seg_shift(reg);
    const int stride = 1 << sh;
    const int lb = b - seg_bucketbase(reg);
    const int row_base_local = lb << sh;
    int nrows = seg_rows(reg) - row_base_local;
    if (nrows > stride) nrows = stride;
    const long long slot = seg_arenabase(reg) + (long long)lb * seg_cap(reg);
    const int count = gcursor[b];
    const int fbase = bbase[b];

    for (int i = t; i < 1024; i += 256) hist[i] = 0;
    __syncthreads();

    for (int j = t; j < count; j += 256) {
        int key = arena[slot + j].x;
        atomicAdd(&hist[key >> 17], 1);
    }
    __syncthreads();

    {
        const int lane = t & 63, wave = t >> 6;
        int v[4]; int s = 0;
#pragma unroll
        for (int q = 0; q < 4; ++q) { v[q] = hist[t * 4 + q]; s += v[q]; }
        int inc = s;
        for (int d = 1; d < 64; d <<= 1) {
            int u = __shfl_up(inc, d, 64);
            if (lane >= d) inc += u;
        }
        if (lane == 63) wsum[wave] = inc;
        __syncthreads();
        int woff = 0;
        for (int w = 0; w < wave; ++w) woff += wsum[w];
        int run = woff + inc - s;
#pragma unroll
        for (int q = 0; q < 4; ++q) { excl[t * 4 + q] = run; run += v[q]; }
    }
    __syncthreads();

    const int grow0 = seg_rowbase(reg) + row_base_local;
    for (int r = t; r < nrows; r += 256)
        rp[grow0 + r] = fbase + excl[r];
    __syncthreads();

    for (int j = t; j < count; j += 256) {
        int2 e = arena[slot + j];
        int r = e.x >> 17;
        int pos = atomicAdd(&excl[r], 1);
        cv[fbase + pos] = make_int2((e.x & 0x1FFFF) << 6, e.y);
    }
}

// ---------------- SpMM gather: group-of-4 dwordx4 scheme ----------------
// Lane group g = lane>>4 handles nnz j+g; each lane loads 16 B of row col[j+g]
// (1 KB / wave-instruction = 4 nnz). acc[8] covers dims (lane&15)*8 .. +7.
// Cross-group reduction (shfl_xor 16/32) once per output row.
__device__ __forceinline__ void walk_row_g4(
    const int2* __restrict__ cv, int start, int end, int lane,
    const unsigned* __restrict__ xb, float* acc)
{
    const int g   = lane >> 4;
    const int p16 = (lane & 15) * 4;   // uint offset within 64-uint row

    for (int sb = start; sb < end; sb += 64) {
        int nn = end - sb; if (nn > 64) nn = 64;
        int2 mycv = make_int2(0, 0);
        if (lane < nn) mycv = cv[sb + lane];
        const int nn1 = nn - 1;
#pragma unroll 2
        for (int jb = 0; jb < nn; jb += 4) {
            int idx  = jb + g;
            int idxc = idx < nn1 ? idx : nn1;
            int   cs = __shfl(mycv.x, idxc, 64);
            float vs = __shfl(__int_as_float(mycv.y), idxc, 64);
            vs = (idx <= nn1) ? vs : 0.0f;
            const uint4 u = *reinterpret_cast<const uint4*>(xb + cs + p16);
            acc[0] = fmaf(vs, bf_lo(u.x), acc[0]);
            acc[1] = fmaf(vs, bf_hi(u.x), acc[1]);
            acc[2] = fmaf(vs, bf_lo(u.y), acc[2]);
            acc[3] = fmaf(vs, bf_hi(u.y), acc[3]);
            acc[4] = fmaf(vs, bf_lo(u.z), acc[4]);
            acc[5] = fmaf(vs, bf_hi(u.z), acc[5]);
            acc[6] = fmaf(vs, bf_lo(u.w), acc[6]);
            acc[7] = fmaf(vs, bf_hi(u.w), acc[7]);
        }
    }
}

__device__ __forceinline__ void reduce_groups(float* acc)
{
#pragma unroll
    for (int e = 0; e < 8; ++e) {
        acc[e] += __shfl_xor(acc[e], 16, 64);
        acc[e] += __shfl_xor(acc[e], 32, 64);
    }
}

// stage 1: h1 = p1 @ ego, h2 = l1 @ ego   (outputs bf16)
__global__ __launch_bounds__(256) void spmm_stage1_kernel(
    const int* __restrict__ rp, const int2* __restrict__ cv,
    const unsigned* __restrict__ ego_bf,
    unsigned* __restrict__ h1, unsigned* __restrict__ h2)
{
    int wid = (blockIdx.x * 256 + threadIdx.x) >> 6;
    int lane = threadIdx.x & 63;
    if (wid >= 2 * N_HE) return;
    int rbase; unsigned* y;
    if (wid < N_HE) { rbase = RB_P1 + wid;           y = h1 + wid * 64; }
    else            { rbase = RB_L1 + (wid - N_HE);  y = h2 + (wid - N_HE) * 64; }

    float acc[8] = {0, 0, 0, 0, 0, 0, 0, 0};
    walk_row_g4(cv, rp[rbase], rp[rbase + 1], lane, ego_bf, acc);
    reduce_groups(acc);

    if (lane < 16) {
        uint4 o;
        o.x = pack_bf16(acc[0], acc[1]);
        o.y = pack_bf16(acc[2], acc[3]);
        o.z = pack_bf16(acc[4], acc[5]);
        o.w = pack_bf16(acc[6], acc[7]);
        *reinterpret_cast<uint4*>(y + lane * 4) = o;
    }
}

// stage 2: side = A@ego + p2@h1 + l2@h2   (output fp32)
__global__ __launch_bounds__(256) void spmm_stage2_kernel(
    const int* __restrict__ rp, const int2* __restrict__ cv,
    const unsigned* __restrict__ ego_bf,
    const unsigned* __restrict__ h1, const unsigned* __restrict__ h2,
    float* __restrict__ side)
{
    int wid = (blockIdx.x * 256 + threadIdx.x) >> 6;
    int lane = threadIdx.x & 63;
    if (wid >= N_ENT) return;

    float acc[8] = {0, 0, 0, 0, 0, 0, 0, 0};
    walk_row_g4(cv, rp[RB_A  + wid], rp[RB_A  + wid + 1], lane, ego_bf, acc);
    walk_row_g4(cv, rp[RB_P2 + wid], rp[RB_P2 + wid + 1], lane, h1, acc);
    walk_row_g4(cv, rp[RB_L2 + wid], rp[RB_L2 + wid + 1], lane, h2, acc);
    reduce_groups(acc);

    if (lane < 16) {
        float* yp = side + (long long)wid * DD + lane * 8;
        float4 a0 = make_float4(acc[0], acc[1], acc[2], acc[3]);
        float4 a1 = make_float4(acc[4], acc[5], acc[6], acc[7]);
        *reinterpret_cast<float4*>(yp)     = a0;
        *reinterpret_cast<float4*>(yp + 4) = a1;
    }
}

// ---------------- MFMA dense epilogue ----------------
union BfFrag { unsigned u[4]; bf16x8 v; };

__global__ __launch_bounds__(256) void dense_mfma_kernel(
    const float* __restrict__ ego, const float* __restrict__ side,
    const float* __restrict__ W1, const float* __restrict__ b1,
    const float* __restrict__ W2, const float* __restrict__ b2,
    float* __restrict__ out)
{
    __shared__ unsigned Wb1[8192];   // 32 KB: W1 bf16, swizzled
    __shared__ unsigned Wb2[8192];   // 32 KB: W2 bf16, swizzled

    const int tid = threadIdx.x;

    for (int idx = tid; idx < 8192; idx += 256) {
        int row = idx >> 6, pc = idx & 63;
        unsigned pk1 = pack_bf16(W1[row * 128 + pc * 2], W1[row * 128 + pc * 2 + 1]);
        unsigned pk2 = pack_bf16(W2[row * 128 + pc * 2], W2[row * 128 + pc * 2 + 1]);
        int boff = row * 256 + ((pc * 4) ^ ((row & 7) << 4));
        *(unsigned*)((char*)Wb1 + boff) = pk1;
        *(unsigned*)((char*)Wb2 + boff) = pk2;
    }
    __syncthreads();

    const int wave = tid >> 6;
    const int lane = tid & 63;
    const int m    = lane & 15;
    const int kg   = lane >> 4;

    float bs[8], bb[8];
#pragma unroll
    for (int c = 0; c < 8; ++c) {
        bs[c] = b1[c * 16 + m];
        bb[c] = b2[c * 16 + m];
    }

    for (int wt = blockIdx.x * 4 + wave; wt < 3125; wt += gridDim.x * 4) {
        const int grow = wt * 32;
        const long long r0 = (long long)(grow + m) * DD;
        const long long r1 = (long long)(grow + 16 + m) * DD;

        f32x4 accS0[8], accS1[8], accB0[8], accB1[8];
#pragma unroll
        for (int c = 0; c < 8; ++c) {
            accS0[c] = (f32x4)0.0f; accS1[c] = (f32x4)0.0f;
            accB0[c] = (f32x4)0.0f; accB1[c] = (f32x4)0.0f;
        }

#pragma unroll 1
        for (int kk = 0; kk < 4; ++kk) {
            const int kb = kk * 32 + kg * 8;

            float4 e0a = *(const float4*)(ego  + r0 + kb);
            float4 e0b = *(const float4*)(ego  + r0 + kb + 4);
            float4 s0a = *(const float4*)(side + r0 + kb);
            float4 s0b = *(const float4*)(side + r0 + kb + 4);
            float4 e1a = *(const float4*)(ego  + r1 + kb);
            float4 e1b = *(const float4*)(ego  + r1 + kb + 4);
            float4 s1a = *(const float4*)(side + r1 + kb);
            float4 s1b = *(const float4*)(side + r1 + kb + 4);

            BfFrag aS0, aB0, aS1, aB1;
            aS0.u[0] = pack_bf16(e0a.x + s0a.x, e0a.y + s0a.y);
            aS0.u[1] = pack_bf16(e0a.z + s0a.z, e0a.w + s0a.w);
            aS0.u[2] = pack_bf16(e0b.x + s0b.x, e0b.y + s0b.y);
            aS0.u[3] = pack_bf16(e0b.z + s0b.z, e0b.w + s0b.w);
            aB0.u[0] = pack_bf16(e0a.x * s0a.x, e0a.y * s0a.y);
            aB0.u[1] = pack_bf16(e0a.z * s0a.z, e0a.w * s0a.w);
            aB0.u[2] = pack_bf16(e0b.x * s0b.x, e0b.y * s0b.y);
            aB0.u[3] = pack_bf16(e0b.z * s0b.z, e0b.w * s0b.w);
            aS1.u[0] = pack_bf16(e1a.x + s1a.x, e1a.y + s1a.y);
            aS1.u[1] = pack_bf16(e1a.z + s1a.z, e1a.w + s1a.w);
            aS1.u[2] = pack_bf16(e1b.x + s1b.x, e1b.y + s1b.y);
            aS1.u[3] = pack_bf16(e1b.z + s1b.z, e1b.w + s1b.w);
            aB1.u[0] = pack_bf16(e1a.x * s1a.x, e1a.y * s1a.y);
            aB1.u[1] = pack_bf16(e1a.z * s1a.z, e1a.w * s1a.w);
            aB1.u[2] = pack_bf16(e1b.x * s1b.x, e1b.y * s1b.y);
            aB1.u[3] = pack_bf16(e1b.z * s1b.z, e1b.w * s1b.w);

#pragma unroll
            for (int c = 0; c < 8; ++c) {
                int wrow = c * 16 + m;
                int boff = wrow * 256 + ((kk * 64 + (kg << 4)) ^ ((wrow & 7) << 4));
                bf16x8 w1 = *(const bf16x8*)((const char*)Wb1 + boff);
                bf16x8 w2 = *(const bf16x8*)((const char*)Wb2 + boff);
                accS0[c] = __builtin_amdgcn_mfma_f32_16x16x32_bf16(aS0.v, w1, accS0[c], 0, 0, 0);
                accS1[c] = __builtin_amdgcn_mfma_f32_16x16x32_bf16(aS1.v, w1, accS1[c], 0, 0, 0);
                accB0[c] = __builtin_amdgcn_mfma_f32_16x16x32_bf16(aB0.v, w2, accB0[c], 0, 0, 0);
                accB1[c] = __builtin_amdgcn_mfma_f32_16x16x32_bf16(aB1.v, w2, accB1[c], 0, 0, 0);
            }
        }

#pragma unroll
        for (int c = 0; c < 8; ++c) {
#pragma unroll
            for (int q = 0; q < 4; ++q) {
                int orow = grow + kg * 4 + q;
                out[(long long)orow * DD + c * 16 + m] =
                    lrelu(accS0[c][q] + bs[c]) + lrelu(accB0[c][q] + bb[c]);
                out[(long long)(orow + 16) * DD + c * 16 + m] =
                    lrelu(accS1[c][q] + bs[c]) + lrelu(accB1[c][q] + bb[c]);
            }
        }
    }
}

extern "C" void kernel_launch(void* const* d_in, const int* in_sizes, int n_in,
                              void* d_out, int out_size, void* d_ws, size_t ws_size,
                              hipStream_t stream)
{
    const float* ego = (const float*)d_in[0];
    const float* W1  = (const float*)d_in[16];
    const float* b1  = (const float*)d_in[17];
    const float* W2  = (const float*)d_in[18];
    const float* b2  = (const float*)d_in[19];

    BuildArgs a;
    a.rows[0] = (const int*)d_in[1];  a.cols[0] = (const int*)d_in[2];  a.vals[0] = (const float*)d_in[3];
    a.rows[1] = (const int*)d_in[4];  a.cols[1] = (const int*)d_in[5];  a.vals[1] = (const float*)d_in[6];
    a.rows[2] = (const int*)d_in[7];  a.cols[2] = (const int*)d_in[8];  a.vals[2] = (const float*)d_in[9];
    a.rows[3] = (const int*)d_in[10]; a.cols[3] = (const int*)d_in[11]; a.vals[3] = (const float*)d_in[12];
    a.rows[4] = (const int*)d_in[13]; a.cols[4] = (const int*)d_in[14]; a.vals[4] = (const float*)d_in[15];
    int nnz[5] = { in_sizes[1], in_sizes[4], in_sizes[7], in_sizes[10], in_sizes[13] };
    a.nnzbase[0] = 0;
    for (int s = 0; s < 5; ++s) a.nnzbase[s + 1] = a.nnzbase[s] + nnz[s];
    const int total = a.nnzbase[5];

    // ---- workspace carve (arena time-shares the side region) ----
    char* p = (char*)d_ws;
    float*    side    = (float*)p;
    int2*     arena   = (int2*)p;         p += (size_t)N_ENT * DD * 4;       // 51.2 MB (arena needs 48.8)
    unsigned* ego_bf  = (unsigned*)p;     p += (size_t)N_ENT * 64 * 4;       // 25.6 MB
    unsigned* h1      = (unsigned*)p;     p += (size_t)N_HE  * 64 * 4;       // 5.12 MB
    unsigned* h2      = (unsigned*)p;     p += (size_t)N_HE  * 64 * 4;       // 5.12 MB
    int2*     cv      = (int2*)p;         p += (size_t)total * 8;            // 44.8 MB
    int*      rp      = (int*)p;          p += 340224 * 4;
    int*      gcursor = (int*)p;          p += 512 * 4;
    int*      bbase   = (int*)p;          p += 512 * 4;

    // build
    hipMemsetAsync(gcursor, 0, NB * sizeof(int), stream);
    convert_bf16_kernel<<<(N_ENT * 64 + 255) / 256, 256, 0, stream>>>(ego, ego_bf, N_ENT * 64);
    const int nblk_part = (total + TILE - 1) / TILE;
    partition_kernel<<<nblk_part, 256, 0, stream>>>(a, gcursor, arena);
    bucket_scan_kernel<<<1, 512, 0, stream>>>(gcursor, bbase, rp);
    bucket_sort_kernel<<<NB, 256, 0, stream>>>(gcursor, bbase, arena, cv, rp);

    // spmm (arena region is dead from here; side reuses it)
    spmm_stage1_kernel<<<(2 * N_HE) / 4, 256, 0, stream>>>(rp, cv, ego_bf, h1, h2);
    spmm_stage2_kernel<<<N_ENT / 4, 256, 0, stream>>>(rp, cv, ego_bf, h1, h2, side);

    // dense epilogue (MFMA)
    dense_mfma_kernel<<<512, 256, 0, stream>>>(ego, side, W1, b1, W2, b2, (float*)d_out);
}

// Round 8
// 388.690 us; speedup vs baseline: 24.5689x; 1.0951x over previous
//
#include <hip/hip_runtime.h>

#define N_ENT 100000
#define N_HE  20000
#define DD    128

// Global row space (concatenated over the 5 matrices)
#define RB_A   0
#define RB_P1  100000
#define RB_P2  120000
#define RB_L1  220000
#define RB_L2  240000
#define NROWS_TOT 340000

// Bucket geometry: regions {A,P1,P2,L1,L2}
#define NB 452
#define TILE 4096

typedef float f32x4 __attribute__((ext_vector_type(4)));
typedef short bf16x8 __attribute__((ext_vector_type(8)));

__device__ __forceinline__ int bucket_region(int b) {
    return (b < 98) ? 0 : (b < 177) ? 1 : (b < 275) ? 2 : (b < 354) ? 3 : 4;
}
__device__ __forceinline__ int seg_shift(int s)      { return (s == 1 || s == 3) ? 8 : 10; }
__device__ __forceinline__ int seg_bucketbase(int s) { return s == 0 ? 0 : s == 1 ? 98 : s == 2 ? 177 : s == 3 ? 275 : 354; }
__device__ __forceinline__ int seg_cap(int s)        { return s == 0 ? 17408 : (s == 1 || s == 3) ? 13824 : 11264; }
__device__ __forceinline__ long long seg_arenabase(int s) {
    return s == 0 ? 0LL : s == 1 ? 1705984LL : s == 2 ? 2798080LL : s == 3 ? 3901952LL : 4994048LL;
}
__device__ __forceinline__ int seg_rowbase(int s)    { return s == 0 ? 0 : s == 1 ? 100000 : s == 2 ? 120000 : s == 3 ? 220000 : 240000; }
__device__ __forceinline__ int seg_rows(int s)       { return (s == 1 || s == 3) ? 20000 : 100000; }

__device__ __forceinline__ float bf_lo(unsigned u) { return __uint_as_float(u << 16); }
__device__ __forceinline__ float bf_hi(unsigned u) { return __uint_as_float(u & 0xffff0000u); }
__device__ __forceinline__ unsigned short f2bf(float f) {
    unsigned u = __float_as_uint(f);
    unsigned r = (u + 0x7fffu + ((u >> 16) & 1u)) >> 16;   // RNE
    return (unsigned short)r;
}
__device__ __forceinline__ unsigned pack_bf16(float a, float b) {
    return (unsigned)f2bf(a) | ((unsigned)f2bf(b) << 16);
}
__device__ __forceinline__ float lrelu(float x) { return x > 0.0f ? x : 0.01f * x; }
__device__ __forceinline__ float i8f(unsigned u, int b) {
    return (float)((int)(u << (24 - 8 * b)) >> 24);
}

// ---------------- ego fp32 -> block-scaled int8 (one 32-lane half-wave per row) ----------------
__global__ __launch_bounds__(256) void quant_ego_kernel(
    const float* __restrict__ ego, unsigned* __restrict__ ego_q,
    float* __restrict__ ego_scale)
{
    int row = (blockIdx.x * 256 + threadIdx.x) >> 5;
    if (row >= N_ENT) return;
    int l = threadIdx.x & 31;
    const float4 v = *(const float4*)(ego + (long long)row * DD + l * 4);
    float m = fmaxf(fmaxf(fabsf(v.x), fabsf(v.y)), fmaxf(fabsf(v.z), fabsf(v.w)));
    for (int d = 1; d < 32; d <<= 1) m = fmaxf(m, __shfl_xor(m, d, 32));
    float inv = (m > 0.0f) ? 127.0f / m : 0.0f;
    int q0 = __float2int_rn(v.x * inv);
    int q1 = __float2int_rn(v.y * inv);
    int q2 = __float2int_rn(v.z * inv);
    int q3 = __float2int_rn(v.w * inv);
    unsigned pk = (q0 & 255) | ((q1 & 255) << 8) | ((q2 & 255) << 16) | ((q3 & 255) << 24);
    ego_q[row * 32 + l] = pk;
    if (l == 0) ego_scale[row] = m * (1.0f / 127.0f);
}

struct BuildArgs {
    const int*   rows[5];
    const int*   cols[5];
    const float* vals[5];
    int nnzbase[6];
};

__device__ __forceinline__ void seg_of(int i, const int* nnzbase, int& seg, int& li) {
    int s = 0;
    s += (i >= nnzbase[1]);
    s += (i >= nnzbase[2]);
    s += (i >= nnzbase[3]);
    s += (i >= nnzbase[4]);
    seg = s; li = i - nnzbase[s];
}

// ---------------- Phase A: LDS-binned partition into bucket arena ----------------
__global__ __launch_bounds__(256, 4) void partition_kernel(
    BuildArgs a, int* __restrict__ gcursor, int2* __restrict__ arena)
{
    __shared__ int2 staging[TILE];         // 32 KB
    __shared__ int  hist[NB];
    __shared__ int  excl[NB + 1];
    __shared__ int  cursor[NB];
    __shared__ int  gbase[NB];

    const int t = threadIdx.x;
    const int tile_base = blockIdx.x * TILE;
    const int total = a.nnzbase[5];
    int tile_n = total - tile_base;
    if (tile_n > TILE) tile_n = TILE;
    if (tile_n <= 0) return;

    for (int i = t; i < NB; i += 256) hist[i] = 0;
    __syncthreads();

    int pk[16];
#pragma unroll
    for (int q = 0; q < 16; ++q) {
        int j = t + q * 256;
        pk[q] = -1;
        if (j < tile_n) {
            int i = tile_base + j;
            int seg, li; seg_of(i, a.nnzbase, seg, li);
            int row = a.rows[seg][li];
            int sh = seg_shift(seg);
            int b = seg_bucketbase(seg) + (row >> sh);
            int rl = row & ((1 << sh) - 1);
            pk[q] = (b << 10) | rl;
            atomicAdd(&hist[b], 1);
        }
    }
    __syncthreads();

    if (t < 64) {
        int carry = 0;
        for (int base = 0; base < NB; base += 64) {
            int idx = base + t;
            int v = (idx < NB) ? hist[idx] : 0;
            int inc = v;
            for (int d = 1; d < 64; d <<= 1) {
                int u = __shfl_up(inc, d, 64);
                if (t >= d) inc += u;
            }
            if (idx < NB) excl[idx] = carry + inc - v;
            carry += __shfl(inc, 63, 64);
        }
        if (t == 0) excl[NB] = carry;
    }
    __syncthreads();

    for (int b = t; b < NB; b += 256) {
        int c = hist[b];
        gbase[b] = (c > 0) ? atomicAdd(&gcursor[b], c) : 0;
        cursor[b] = excl[b];
    }
    __syncthreads();

#pragma unroll
    for (int q = 0; q < 16; ++q) {
        int j = t + q * 256;
        if (j < tile_n) {
            int i = tile_base + j;
            int seg, li; seg_of(i, a.nnzbase, seg, li);
            int col = a.cols[seg][li];
            float v = a.vals[seg][li];
            int b = pk[q] >> 10;
            int rl = pk[q] & 1023;
            int pos = atomicAdd(&cursor[b], 1);
            staging[pos] = make_int2((rl << 17) | col, __float_as_int(v));
        }
    }
    __syncthreads();

    for (int p = t; p < tile_n; p += 256) {
        int lo = 0, hi = NB;
#pragma unroll
        for (int it = 0; it < 9; ++it) {
            int mid = (lo + hi) >> 1;
            if (excl[mid] <= p) lo = mid; else hi = mid;
        }
        int b = lo;
        int reg = bucket_region(b);
        long long slot = seg_arenabase(reg) + (long long)(b - seg_bucketbase(reg)) * seg_cap(reg);
        arena[slot + gbase[b] + (p - excl[b])] = staging[p];
    }
}

// ---------------- bucket-count exclusive scan ----------------
__global__ __launch_bounds__(512) void bucket_scan_kernel(
    const int* __restrict__ gcursor, int* __restrict__ bbase, int* __restrict__ rp)
{
    __shared__ int tmp[512];
    int t = threadIdx.x;
    int v = (t < NB) ? gcursor[t] : 0;
    tmp[t] = v;
    __syncthreads();
    for (int d = 1; d < 512; d <<= 1) {
        int u = (t >= d) ? tmp[t - d] : 0;
        __syncthreads();
        tmp[t] += u;
        __syncthreads();
    }
    if (t < NB) bbase[t] = tmp[t] - v;
    if (t == NB - 1) rp[NROWS_TOT] = tmp[t];
}

// ---------------- Phase B: per-bucket counting sort -> final cv + rp ----------------
// Regions A/P1/L1 gather from ego: fold ego_scale[col] into the value here.
__global__ __launch_bounds__(256) void bucket_sort_kernel(
    const int* __restrict__ gcursor, const int* __restrict__ bbase,
    const int2* __restrict__ arena, const float* __restrict__ ego_scale,
    int2* __restrict__ cv, int* __restrict__ rp)
{
    __shared__ int hist[1024];
    __shared__ int excl[1024];
    __shared__ int wsum[4];

    const int b = blockIdx.x;
    const int t = threadIdx.x;
    const int reg = bucket_region(b);
    const int sh = seg_shift(reg);
    const int stride = 1 << sh;
    const int lb = b - seg_bucketbase(reg);
    const int row_base_local = lb << sh;
    int nrows = seg_rows(reg) - row_base_local;
    if (nrows > stride) nrows = stride;
    const long long slot = seg_arenabase(reg) + (long long)lb * seg_cap(reg);
    const int count = gcursor[b];
    const int fbase = bbase[b];
    const bool fold = (reg == 0) || (reg == 1) || (reg == 3);

    for (int i = t; i < 1024; i += 256) hist[i] = 0;
    __syncthreads();

    for (int j = t; j < count; j += 256) {
        int key = arena[slot + j].x;
        atomicAdd(&hist[key >> 17], 1);
    }
    __syncthreads();

    {
        const int lane = t & 63, wave = t >> 6;
        int v[4]; int s = 0;
#pragma unroll
        for (int q = 0; q < 4; ++q) { v[q] = hist[t * 4 + q]; s += v[q]; }
        int inc = s;
        for (int d = 1; d < 64; d <<= 1) {
            int u = __shfl_up(inc, d, 64);
            if (lane >= d) inc += u;
        }
        if (lane == 63) wsum[wave] = inc;
        __syncthreads();
        int woff = 0;
        for (int w = 0; w < wave; ++w) woff += wsum[w];
        int run = woff + inc - s;
#pragma unroll
        for (int q = 0; q < 4; ++q) { excl[t * 4 + q] = run; run += v[q]; }
    }
    __syncthreads();

    const int grow0 = seg_rowbase(reg) + row_base_local;
    for (int r = t; r < nrows; r += 256)
        rp[grow0 + r] = fbase + excl[r];
    __syncthreads();

    for (int j = t; j < count; j += 256) {
        int2 e = arena[slot + j];
        int r = e.x >> 17;
        int c = e.x & 0x1FFFF;
        float v = __int_as_float(e.y);
        if (fold) v *= ego_scale[c];
        int pos = atomicAdd(&excl[r], 1);
        cv[fbase + pos] = make_int2(c, __float_as_int(v));
    }
}

// ---------------- SpMM gather walks (group-of-4 scheme) ----------------
// int8 walk: row = 128 B (one cache line). Lane covers dims (lane&15)*8..+7 via uint2.
__device__ __forceinline__ void walk_row_i8(
    const int2* __restrict__ cv, int start, int end, int lane,
    const unsigned* __restrict__ xq, float* acc)
{
    const int g  = lane >> 4;
    const int p8 = (lane & 15) * 2;

    for (int sb = start; sb < end; sb += 64) {
        int nn = end - sb; if (nn > 64) nn = 64;
        int2 mycv = make_int2(0, 0);
        if (lane < nn) mycv = cv[sb + lane];
        const int nn1 = nn - 1;
#pragma unroll 2
        for (int jb = 0; jb < nn; jb += 4) {
            int idx  = jb + g;
            int idxc = idx < nn1 ? idx : nn1;
            int   cs = __shfl(mycv.x, idxc, 64);
            float vs = __shfl(__int_as_float(mycv.y), idxc, 64);
            vs = (idx <= nn1) ? vs : 0.0f;
            const uint2 u = *reinterpret_cast<const uint2*>(xq + cs * 32 + p8);
            acc[0] = fmaf(vs, i8f(u.x, 0), acc[0]);
            acc[1] = fmaf(vs, i8f(u.x, 1), acc[1]);
            acc[2] = fmaf(vs, i8f(u.x, 2), acc[2]);
            acc[3] = fmaf(vs, i8f(u.x, 3), acc[3]);
            acc[4] = fmaf(vs, i8f(u.y, 0), acc[4]);
            acc[5] = fmaf(vs, i8f(u.y, 1), acc[5]);
            acc[6] = fmaf(vs, i8f(u.y, 2), acc[6]);
            acc[7] = fmaf(vs, i8f(u.y, 3), acc[7]);
        }
    }
}

// bf16 walk: row = 256 B (64 uints). Lane covers dims (lane&15)*8..+7 via uint4.
__device__ __forceinline__ void walk_row_bf(
    const int2* __restrict__ cv, int start, int end, int lane,
    const unsigned* __restrict__ xb, float* acc)
{
    const int g   = lane >> 4;
    const int p16 = (lane & 15) * 4;

    for (int sb = start; sb < end; sb += 64) {
        int nn = end - sb; if (nn > 64) nn = 64;
        int2 mycv = make_int2(0, 0);
        if (lane < nn) mycv = cv[sb + lane];
        const int nn1 = nn - 1;
#pragma unroll 2
        for (int jb = 0; jb < nn; jb += 4) {
            int idx  = jb + g;
            int idxc = idx < nn1 ? idx : nn1;
            int   cs = __shfl(mycv.x, idxc, 64);
            float vs = __shfl(__int_as_float(mycv.y), idxc, 64);
            vs = (idx <= nn1) ? vs : 0.0f;
            const uint4 u = *reinterpret_cast<const uint4*>(xb + cs * 64 + p16);
            acc[0] = fmaf(vs, bf_lo(u.x), acc[0]);
            acc[1] = fmaf(vs, bf_hi(u.x), acc[1]);
            acc[2] = fmaf(vs, bf_lo(u.y), acc[2]);
            acc[3] = fmaf(vs, bf_hi(u.y), acc[3]);
            acc[4] = fmaf(vs, bf_lo(u.z), acc[4]);
            acc[5] = fmaf(vs, bf_hi(u.z), acc[5]);
            acc[6] = fmaf(vs, bf_lo(u.w), acc[6]);
            acc[7] = fmaf(vs, bf_hi(u.w), acc[7]);
        }
    }
}

__device__ __forceinline__ void reduce_groups(float* acc)
{
#pragma unroll
    for (int e = 0; e < 8; ++e) {
        acc[e] += __shfl_xor(acc[e], 16, 64);
        acc[e] += __shfl_xor(acc[e], 32, 64);
    }
}

// stage 1: h1 = p1 @ ego, h2 = l1 @ ego   (int8 gather, bf16 outputs)
__global__ __launch_bounds__(256) void spmm_stage1_kernel(
    const int* __restrict__ rp, const int2* __restrict__ cv,
    const unsigned* __restrict__ ego_q,
    unsigned* __restrict__ h1, unsigned* __restrict__ h2)
{
    int wid = (blockIdx.x * 256 + threadIdx.x) >> 6;
    int lane = threadIdx.x & 63;
    if (wid >= 2 * N_HE) return;
    int rbase; unsigned* y;
    if (wid < N_HE) { rbase = RB_P1 + wid;           y = h1 + wid * 64; }
    else            { rbase = RB_L1 + (wid - N_HE);  y = h2 + (wid - N_HE) * 64; }

    float acc[8] = {0, 0, 0, 0, 0, 0, 0, 0};
    walk_row_i8(cv, rp[rbase], rp[rbase + 1], lane, ego_q, acc);
    reduce_groups(acc);

    if (lane < 16) {
        uint4 o;
        o.x = pack_bf16(acc[0], acc[1]);
        o.y = pack_bf16(acc[2], acc[3]);
        o.z = pack_bf16(acc[4], acc[5]);
        o.w = pack_bf16(acc[6], acc[7]);
        *reinterpret_cast<uint4*>(y + lane * 4) = o;
    }
}

// stage 2: side = A@ego (int8) + p2@h1 + l2@h2 (bf16)   (output fp32)
__global__ __launch_bounds__(256) void spmm_stage2_kernel(
    const int* __restrict__ rp, const int2* __restrict__ cv,
    const unsigned* __restrict__ ego_q,
    const unsigned* __restrict__ h1, const unsigned* __restrict__ h2,
    float* __restrict__ side)
{
    int wid = (blockIdx.x * 256 + threadIdx.x) >> 6;
    int lane = threadIdx.x & 63;
    if (wid >= N_ENT) return;

    float acc[8] = {0, 0, 0, 0, 0, 0, 0, 0};
    walk_row_i8(cv, rp[RB_A  + wid], rp[RB_A  + wid + 1], lane, ego_q, acc);
    walk_row_bf(cv, rp[RB_P2 + wid], rp[RB_P2 + wid + 1], lane, h1, acc);
    walk_row_bf(cv, rp[RB_L2 + wid], rp[RB_L2 + wid + 1], lane, h2, acc);
    reduce_groups(acc);

    if (lane < 16) {
        float* yp = side + (long long)wid * DD + (lane & 15) * 8;
        float4 a0 = make_float4(acc[0], acc[1], acc[2], acc[3]);
        float4 a1 = make_float4(acc[4], acc[5], acc[6], acc[7]);
        *reinterpret_cast<float4*>(yp)     = a0;
        *reinterpret_cast<float4*>(yp + 4) = a1;
    }
}

// ---------------- MFMA dense epilogue (512 threads, 16 rows/wave) ----------------
union BfFrag { unsigned u[4]; bf16x8 v; };

__global__ __launch_bounds__(512, 4) void dense_mfma_kernel(
    const float* __restrict__ ego, const float* __restrict__ side,
    const float* __restrict__ W1, const float* __restrict__ b1,
    const float* __restrict__ W2, const float* __restrict__ b2,
    float* __restrict__ out)
{
    __shared__ unsigned Wb1[8192];   // 32 KB: W1 bf16, swizzled
    __shared__ unsigned Wb2[8192];   // 32 KB: W2 bf16, swizzled

    const int tid = threadIdx.x;

    for (int idx = tid; idx < 8192; idx += 512) {
        int row = idx >> 6, pc = idx & 63;
        unsigned pk1 = pack_bf16(W1[row * 128 + pc * 2], W1[row * 128 + pc * 2 + 1]);
        unsigned pk2 = pack_bf16(W2[row * 128 + pc * 2], W2[row * 128 + pc * 2 + 1]);
        int boff = row * 256 + ((pc * 4) ^ ((row & 7) << 4));
        *(unsigned*)((char*)Wb1 + boff) = pk1;
        *(unsigned*)((char*)Wb2 + boff) = pk2;
    }
    __syncthreads();

    const int wave = tid >> 6;   // 0..7
    const int lane = tid & 63;
    const int m    = lane & 15;
    const int kg   = lane >> 4;

    float bs[8], bb[8];
#pragma unroll
    for (int c = 0; c < 8; ++c) {
        bs[c] = b1[c * 16 + m];
        bb[c] = b2[c * 16 + m];
    }

    for (int wt = blockIdx.x * 8 + wave; wt < 6250; wt += gridDim.x * 8) {
        const long long r0 = (long long)(wt * 16 + m) * DD;

        f32x4 accS[8], accB[8];
#pragma unroll
        for (int c = 0; c < 8; ++c) { accS[c] = (f32x4)0.0f; accB[c] = (f32x4)0.0f; }

#pragma unroll 1
        for (int kk = 0; kk < 4; ++kk) {
            const int kb = kk * 32 + kg * 8;

            float4 ea = *(const float4*)(ego  + r0 + kb);
            float4 eb = *(const float4*)(ego  + r0 + kb + 4);
            float4 sa = *(const float4*)(side + r0 + kb);
            float4 sb = *(const float4*)(side + r0 + kb + 4);

            BfFrag aS, aB;
            aS.u[0] = pack_bf16(ea.x + sa.x, ea.y + sa.y);
            aS.u[1] = pack_bf16(ea.z + sa.z, ea.w + sa.w);
            aS.u[2] = pack_bf16(eb.x + sb.x, eb.y + sb.y);
            aS.u[3] = pack_bf16(eb.z + sb.z, eb.w + sb.w);
            aB.u[0] = pack_bf16(ea.x * sa.x, ea.y * sa.y);
            aB.u[1] = pack_bf16(ea.z * sa.z, ea.w * sa.w);
            aB.u[2] = pack_bf16(eb.x * sb.x, eb.y * sb.y);
            aB.u[3] = pack_bf16(eb.z * sb.z, eb.w * sb.w);

#pragma unroll
            for (int c = 0; c < 8; ++c) {
                int wrow = c * 16 + m;
                int boff = wrow * 256 + ((kk * 64 + (kg << 4)) ^ ((wrow & 7) << 4));
                bf16x8 w1 = *(const bf16x8*)((const char*)Wb1 + boff);
                bf16x8 w2 = *(const bf16x8*)((const char*)Wb2 + boff);
                accS[c] = __builtin_amdgcn_mfma_f32_16x16x32_bf16(aS.v, w1, accS[c], 0, 0, 0);
                accB[c] = __builtin_amdgcn_mfma_f32_16x16x32_bf16(aB.v, w2, accB[c], 0, 0, 0);
            }
        }

        // D mapping: col = lane&15 (=m), row = kg*4 + q
#pragma unroll
        for (int c = 0; c < 8; ++c) {
#pragma unroll
            for (int q = 0; q < 4; ++q) {
                int orow = wt * 16 + kg * 4 + q;
                out[(long long)orow * DD + c * 16 + m] =
                    lrelu(accS[c][q] + bs[c]) + lrelu(accB[c][q] + bb[c]);
            }
        }
    }
}

extern "C" void kernel_launch(void* const* d_in, const int* in_sizes, int n_in,
                              void* d_out, int out_size, void* d_ws, size_t ws_size,
                              hipStream_t stream)
{
    const float* ego = (const float*)d_in[0];
    const float* W1  = (const float*)d_in[16];
    const float* b1  = (const float*)d_in[17];
    const float* W2  = (const float*)d_in[18];
    const float* b2  = (const float*)d_in[19];

    BuildArgs a;
    a.rows[0] = (const int*)d_in[1];  a.cols[0] = (const int*)d_in[2];  a.vals[0] = (const float*)d_in[3];
    a.rows[1] = (const int*)d_in[4];  a.cols[1] = (const int*)d_in[5];  a.vals[1] = (const float*)d_in[6];
    a.rows[2] = (const int*)d_in[7];  a.cols[2] = (const int*)d_in[8];  a.vals[2] = (const float*)d_in[9];
    a.rows[3] = (const int*)d_in[10]; a.cols[3] = (const int*)d_in[11]; a.vals[3] = (const float*)d_in[12];
    a.rows[4] = (const int*)d_in[13]; a.cols[4] = (const int*)d_in[14]; a.vals[4] = (const float*)d_in[15];
    int nnz[5] = { in_sizes[1], in_sizes[4], in_sizes[7], in_sizes[10], in_sizes[13] };
    a.nnzbase[0] = 0;
    for (int s = 0; s < 5; ++s) a.nnzbase[s + 1] = a.nnzbase[s] + nnz[s];
    const int total = a.nnzbase[5];

    // ---- workspace carve (arena time-shares the side region) ----
    char* p = (char*)d_ws;
    float*    side     = (float*)p;
    int2*     arena    = (int2*)p;        p += (size_t)N_ENT * DD * 4;       // 51.2 MB (arena needs 48.8)
    unsigned* ego_q    = (unsigned*)p;    p += (size_t)N_ENT * 32 * 4;       // 12.8 MB (int8 rows, 128 B)
    float*    ego_scale= (float*)p;       p += (size_t)100096 * 4;           // 400 KB
    unsigned* h1       = (unsigned*)p;    p += (size_t)N_HE * 64 * 4;        // 5.12 MB (bf16 rows)
    unsigned* h2       = (unsigned*)p;    p += (size_t)N_HE * 64 * 4;        // 5.12 MB
    int2*     cv       = (int2*)p;        p += (size_t)total * 8;            // 44.8 MB
    int*      rp       = (int*)p;         p += 340224 * 4;
    int*      gcursor  = (int*)p;         p += 512 * 4;
    int*      bbase    = (int*)p;         p += 512 * 4;

    // build
    hipMemsetAsync(gcursor, 0, NB * sizeof(int), stream);
    quant_ego_kernel<<<(N_ENT * 32 + 255) / 256, 256, 0, stream>>>(ego, ego_q, ego_scale);
    const int nblk_part = (total + TILE - 1) / TILE;
    partition_kernel<<<nblk_part, 256, 0, stream>>>(a, gcursor, arena);
    bucket_scan_kernel<<<1, 512, 0, stream>>>(gcursor, bbase, rp);
    bucket_sort_kernel<<<NB, 256, 0, stream>>>(gcursor, bbase, arena, ego_scale, cv, rp);

    // spmm (arena region is dead from here; side reuses it)
    spmm_stage1_kernel<<<(2 * N_HE) / 4, 256, 0, stream>>>(rp, cv, ego_q, h1, h2);
    spmm_stage2_kernel<<<N_ENT / 4, 256, 0, stream>>>(rp, cv, ego_q, h1, h2, side);

    // dense epilogue (MFMA, 512-thread blocks)
    dense_mfma_kernel<<<782, 512, 0, stream>>>(ego, side, W1, b1, W2, b2, (float*)d_out);
}

// Round 9
// 376.825 us; speedup vs baseline: 25.3425x; 1.0315x over previous
//
#include <hip/hip_runtime.h>

#define N_ENT 100000
#define N_HE  20000
#define DD    128

// Global row space (concatenated over the 5 matrices)
#define RB_A   0
#define RB_P1  100000
#define RB_P2  120000
#define RB_L1  220000
#define RB_L2  240000
#define NROWS_TOT 340000

// Bucket geometry: regions {A,P1,P2,L1,L2}
#define NB 452
#define TILE 3072
#define EPT  12   // entries per thread = TILE/256

typedef float f32x4 __attribute__((ext_vector_type(4)));
typedef short bf16x8 __attribute__((ext_vector_type(8)));

__device__ __forceinline__ int bucket_region(int b) {
    return (b < 98) ? 0 : (b < 177) ? 1 : (b < 275) ? 2 : (b < 354) ? 3 : 4;
}
__device__ __forceinline__ int seg_shift(int s)      { return (s == 1 || s == 3) ? 8 : 10; }
__device__ __forceinline__ int seg_bucketbase(int s) { return s == 0 ? 0 : s == 1 ? 98 : s == 2 ? 177 : s == 3 ? 275 : 354; }
__device__ __forceinline__ int seg_cap(int s)        { return s == 0 ? 17408 : (s == 1 || s == 3) ? 13824 : 11264; }
__device__ __forceinline__ long long seg_arenabase(int s) {
    return s == 0 ? 0LL : s == 1 ? 1705984LL : s == 2 ? 2798080LL : s == 3 ? 3901952LL : 4994048LL;
}
__device__ __forceinline__ int seg_rowbase(int s)    { return s == 0 ? 0 : s == 1 ? 100000 : s == 2 ? 120000 : s == 3 ? 220000 : 240000; }
__device__ __forceinline__ int seg_rows(int s)       { return (s == 1 || s == 3) ? 20000 : 100000; }

__device__ __forceinline__ float bf_lo(unsigned u) { return __uint_as_float(u << 16); }
__device__ __forceinline__ float bf_hi(unsigned u) { return __uint_as_float(u & 0xffff0000u); }
__device__ __forceinline__ unsigned short f2bf(float f) {
    unsigned u = __float_as_uint(f);
    unsigned r = (u + 0x7fffu + ((u >> 16) & 1u)) >> 16;   // RNE
    return (unsigned short)r;
}
__device__ __forceinline__ unsigned pack_bf16(float a, float b) {
    return (unsigned)f2bf(a) | ((unsigned)f2bf(b) << 16);
}
__device__ __forceinline__ float lrelu(float x) { return x > 0.0f ? x : 0.01f * x; }
__device__ __forceinline__ float i8f(unsigned u, int b) {
    return (float)((int)(u << (24 - 8 * b)) >> 24);
}

// ---------------- ego fp32 -> block-scaled int8 (one 32-lane half-wave per row) ----------------
__global__ __launch_bounds__(256) void quant_ego_kernel(
    const float* __restrict__ ego, unsigned* __restrict__ ego_q,
    float* __restrict__ ego_scale)
{
    int row = (blockIdx.x * 256 + threadIdx.x) >> 5;
    if (row >= N_ENT) return;
    int l = threadIdx.x & 31;
    const float4 v = *(const float4*)(ego + (long long)row * DD + l * 4);
    float m = fmaxf(fmaxf(fabsf(v.x), fabsf(v.y)), fmaxf(fabsf(v.z), fabsf(v.w)));
    for (int d = 1; d < 32; d <<= 1) m = fmaxf(m, __shfl_xor(m, d, 32));
    float inv = (m > 0.0f) ? 127.0f / m : 0.0f;
    int q0 = __float2int_rn(v.x * inv);
    int q1 = __float2int_rn(v.y * inv);
    int q2 = __float2int_rn(v.z * inv);
    int q3 = __float2int_rn(v.w * inv);
    unsigned pk = (q0 & 255) | ((q1 & 255) << 8) | ((q2 & 255) << 16) | ((q3 & 255) << 24);
    ego_q[row * 32 + l] = pk;
    if (l == 0) ego_scale[row] = m * (1.0f / 127.0f);
}

struct BuildArgs {
    const int*   rows[5];
    const int*   cols[5];
    const float* vals[5];
    int nnzbase[6];
};

__device__ __forceinline__ void seg_of(int i, const int* nnzbase, int& seg, int& li) {
    int s = 0;
    s += (i >= nnzbase[1]);
    s += (i >= nnzbase[2]);
    s += (i >= nnzbase[3]);
    s += (i >= nnzbase[4]);
    seg = s; li = i - nnzbase[s];
}

// ---------------- Phase A: LDS-binned partition into bucket arena ----------------
// TILE=3072 (12 entries/thread), LDS ~38 KB -> 4 blocks/CU.
// Flush uses a position->bucket map (posb) instead of binary search:
// LDS ops/entry ~7 vs ~13.
__global__ __launch_bounds__(256, 4) void partition_kernel(
    BuildArgs a, int* __restrict__ gcursor, int2* __restrict__ arena)
{
    __shared__ int2 staging[TILE];              // 24 KB
    __shared__ unsigned short posb[TILE];       // 6 KB
    __shared__ int  hist[NB];
    __shared__ int  excl[NB + 1];
    __shared__ int  cursor[NB];
    __shared__ int  gofs[NB];                   // gbase[b] - excl[b]

    const int t = threadIdx.x;
    const int tile_base = blockIdx.x * TILE;
    const int total = a.nnzbase[5];
    int tile_n = total - tile_base;
    if (tile_n > TILE) tile_n = TILE;
    if (tile_n <= 0) return;

    for (int i = t; i < NB; i += 256) hist[i] = 0;
    __syncthreads();

    // pass 1: read rows once, histogram, cache (bucket<<10 | row_local) in regs
    int pk[EPT];
#pragma unroll
    for (int q = 0; q < EPT; ++q) {
        int j = t + q * 256;
        pk[q] = -1;
        if (j < tile_n) {
            int i = tile_base + j;
            int seg, li; seg_of(i, a.nnzbase, seg, li);
            int row = a.rows[seg][li];
            int sh = seg_shift(seg);
            int b = seg_bucketbase(seg) + (row >> sh);
            int rl = row & ((1 << sh) - 1);
            pk[q] = (b << 10) | rl;
            atomicAdd(&hist[b], 1);
        }
    }
    __syncthreads();

    // wave 0: exclusive scan of hist -> excl
    if (t < 64) {
        int carry = 0;
        for (int base = 0; base < NB; base += 64) {
            int idx = base + t;
            int v = (idx < NB) ? hist[idx] : 0;
            int inc = v;
            for (int d = 1; d < 64; d <<= 1) {
                int u = __shfl_up(inc, d, 64);
                if (t >= d) inc += u;
            }
            if (idx < NB) excl[idx] = carry + inc - v;
            carry += __shfl(inc, 63, 64);
        }
        if (t == 0) excl[NB] = carry;
    }
    __syncthreads();

    // reserve global arena ranges; init LDS cursors; fold gbase-excl into gofs
    for (int b = t; b < NB; b += 256) {
        int c = hist[b];
        int e = excl[b];
        int gb = (c > 0) ? atomicAdd(&gcursor[b], c) : 0;
        cursor[b] = e;
        gofs[b] = gb - e;
    }
    __syncthreads();

    // pass 2: read cols/vals, scatter into LDS staging grouped by bucket
#pragma unroll
    for (int q = 0; q < EPT; ++q) {
        int j = t + q * 256;
        if (j < tile_n) {
            int i = tile_base + j;
            int seg, li; seg_of(i, a.nnzbase, seg, li);
            int col = a.cols[seg][li];
            float v = a.vals[seg][li];
            int b = pk[q] >> 10;
            int rl = pk[q] & 1023;
            int pos = atomicAdd(&cursor[b], 1);
            staging[pos] = make_int2((rl << 17) | col, __float_as_int(v));
        }
    }
    __syncthreads();

    // fill position->bucket map (1 LDS write per entry, ~NB/256 buckets per thread)
    for (int b = t; b < NB; b += 256) {
        int lo = excl[b], hi = excl[b + 1];
        for (int p = lo; p < hi; ++p) posb[p] = (unsigned short)b;
    }
    __syncthreads();

    // flush: contiguous, position-ordered (coalesced) writes
    for (int p = t; p < tile_n; p += 256) {
        int b = posb[p];
        int reg = bucket_region(b);
        long long slot = seg_arenabase(reg) + (long long)(b - seg_bucketbase(reg)) * seg_cap(reg);
        arena[slot + gofs[b] + p] = staging[p];
    }
}

// ---------------- bucket-count exclusive scan ----------------
__global__ __launch_bounds__(512) void bucket_scan_kernel(
    const int* __restrict__ gcursor, int* __restrict__ bbase, int* __restrict__ rp)
{
    __shared__ int tmp[512];
    int t = threadIdx.x;
    int v = (t < NB) ? gcursor[t] : 0;
    tmp[t] = v;
    __syncthreads();
    for (int d = 1; d < 512; d <<= 1) {
        int u = (t >= d) ? tmp[t - d] : 0;
        __syncthreads();
        tmp[t] += u;
        __syncthreads();
    }
    if (t < NB) bbase[t] = tmp[t] - v;
    if (t == NB - 1) rp[NROWS_TOT] = tmp[t];
}

// ---------------- Phase B: per-bucket counting sort -> final cv + rp ----------------
// Regions A/P1/L1 gather from ego: fold ego_scale[col] into the value here.
__global__ __launch_bounds__(256) void bucket_sort_kernel(
    const int* __restrict__ gcursor, const int* __restrict__ bbase,
    const int2* __restrict__ arena, const float* __restrict__ ego_scale,
    int2* __restrict__ cv, int* __restrict__ rp)
{
    __shared__ int hist[1024];
    __shared__ int excl[1024];
    __shared__ int wsum[4];

    const int b = blockIdx.x;
    const int t = threadIdx.x;
    const int reg = bucket_region(b);
    const int sh = seg_shift(reg);
    const int stride = 1 << sh;
    const int lb = b - seg_bucketbase(reg);
    const int row_base_local = lb << sh;
    int nrows = seg_rows(reg) - row_base_local;
    if (nrows > stride) nrows = stride;
    const long long slot = seg_arenabase(reg) + (long long)lb * seg_cap(reg);
    const int count = gcursor[b];
    const int fbase = bbase[b];
    const bool fold = (reg == 0) || (reg == 1) || (reg == 3);

    for (int i = t; i < 1024; i += 256) hist[i] = 0;
    __syncthreads();

    for (int j = t; j < count; j += 256) {
        int key = arena[slot + j].x;
        atomicAdd(&hist[key >> 17], 1);
    }
    __syncthreads();

    {
        const int lane = t & 63, wave = t >> 6;
        int v[4]; int s = 0;
#pragma unroll
        for (int q = 0; q < 4; ++q) { v[q] = hist[t * 4 + q]; s += v[q]; }
        int inc = s;
        for (int d = 1; d < 64; d <<= 1) {
            int u = __shfl_up(inc, d, 64);
            if (lane >= d) inc += u;
        }
        if (lane == 63) wsum[wave] = inc;
        __syncthreads();
        int woff = 0;
        for (int w = 0; w < wave; ++w) woff += wsum[w];
        int run = woff + inc - s;
#pragma unroll
        for (int q = 0; q < 4; ++q) { excl[t * 4 + q] = run; run += v[q]; }
    }
    __syncthreads();

    const int grow0 = seg_rowbase(reg) + row_base_local;
    for (int r = t; r < nrows; r += 256)
        rp[grow0 + r] = fbase + excl[r];
    __syncthreads();

    for (int j = t; j < count; j += 256) {
        int2 e = arena[slot + j];
        int r = e.x >> 17;
        int c = e.x & 0x1FFFF;
        float v = __int_as_float(e.y);
        if (fold) v *= ego_scale[c];
        int pos = atomicAdd(&excl[r], 1);
        cv[fbase + pos] = make_int2(c, __float_as_int(v));
    }
}

// ---------------- SpMM gather walks (group-of-4 scheme) ----------------
// int8 walk: row = 128 B (one cache line). Lane covers dims (lane&15)*8..+7 via uint2.
__device__ __forceinline__ void walk_row_i8(
    const int2* __restrict__ cv, int start, int end, int lane,
    const unsigned* __restrict__ xq, float* acc)
{
    const int g  = lane >> 4;
    const int p8 = (lane & 15) * 2;

    for (int sb = start; sb < end; sb += 64) {
        int nn = end - sb; if (nn > 64) nn = 64;
        int2 mycv = make_int2(0, 0);
        if (lane < nn) mycv = cv[sb + lane];
        const int nn1 = nn - 1;
#pragma unroll 2
        for (int jb = 0; jb < nn; jb += 4) {
            int idx  = jb + g;
            int idxc = idx < nn1 ? idx : nn1;
            int   cs = __shfl(mycv.x, idxc, 64);
            float vs = __shfl(__int_as_float(mycv.y), idxc, 64);
            vs = (idx <= nn1) ? vs : 0.0f;
            const uint2 u = *reinterpret_cast<const uint2*>(xq + cs * 32 + p8);
            acc[0] = fmaf(vs, i8f(u.x, 0), acc[0]);
            acc[1] = fmaf(vs, i8f(u.x, 1), acc[1]);
            acc[2] = fmaf(vs, i8f(u.x, 2), acc[2]);
            acc[3] = fmaf(vs, i8f(u.x, 3), acc[3]);
            acc[4] = fmaf(vs, i8f(u.y, 0), acc[4]);
            acc[5] = fmaf(vs, i8f(u.y, 1), acc[5]);
            acc[6] = fmaf(vs, i8f(u.y, 2), acc[6]);
            acc[7] = fmaf(vs, i8f(u.y, 3), acc[7]);
        }
    }
}

// bf16 walk: row = 256 B (64 uints). Lane covers dims (lane&15)*8..+7 via uint4.
__device__ __forceinline__ void walk_row_bf(
    const int2* __restrict__ cv, int start, int end, int lane,
    const unsigned* __restrict__ xb, float* acc)
{
    const int g   = lane >> 4;
    const int p16 = (lane & 15) * 4;

    for (int sb = start; sb < end; sb += 64) {
        int nn = end - sb; if (nn > 64) nn = 64;
        int2 mycv = make_int2(0, 0);
        if (lane < nn) mycv = cv[sb + lane];
        const int nn1 = nn - 1;
#pragma unroll 2
        for (int jb = 0; jb < nn; jb += 4) {
            int idx  = jb + g;
            int idxc = idx < nn1 ? idx : nn1;
            int   cs = __shfl(mycv.x, idxc, 64);
            float vs = __shfl(__int_as_float(mycv.y), idxc, 64);
            vs = (idx <= nn1) ? vs : 0.0f;
            const uint4 u = *reinterpret_cast<const uint4*>(xb + cs * 64 + p16);
            acc[0] = fmaf(vs, bf_lo(u.x), acc[0]);
            acc[1] = fmaf(vs, bf_hi(u.x), acc[1]);
            acc[2] = fmaf(vs, bf_lo(u.y), acc[2]);
            acc[3] = fmaf(vs, bf_hi(u.y), acc[3]);
            acc[4] = fmaf(vs, bf_lo(u.z), acc[4]);
            acc[5] = fmaf(vs, bf_hi(u.z), acc[5]);
            acc[6] = fmaf(vs, bf_lo(u.w), acc[6]);
            acc[7] = fmaf(vs, bf_hi(u.w), acc[7]);
        }
    }
}

__device__ __forceinline__ void reduce_groups(float* acc)
{
#pragma unroll
    for (int e = 0; e < 8; ++e) {
        acc[e] += __shfl_xor(acc[e], 16, 64);
        acc[e] += __shfl_xor(acc[e], 32, 64);
    }
}

// stage 1: h1 = p1 @ ego, h2 = l1 @ ego   (int8 gather, bf16 outputs)
__global__ __launch_bounds__(256) void spmm_stage1_kernel(
    const int* __restrict__ rp, const int2* __restrict__ cv,
    const unsigned* __restrict__ ego_q,
    unsigned* __restrict__ h1, unsigned* __restrict__ h2)
{
    int wid = (blockIdx.x * 256 + threadIdx.x) >> 6;
    int lane = threadIdx.x & 63;
    if (wid >= 2 * N_HE) return;
    int rbase; unsigned* y;
    if (wid < N_HE) { rbase = RB_P1 + wid;           y = h1 + wid * 64; }
    else            { rbase = RB_L1 + (wid - N_HE);  y = h2 + (wid - N_HE) * 64; }

    float acc[8] = {0, 0, 0, 0, 0, 0, 0, 0};
    walk_row_i8(cv, rp[rbase], rp[rbase + 1], lane, ego_q, acc);
    reduce_groups(acc);

    if (lane < 16) {
        uint4 o;
        o.x = pack_bf16(acc[0], acc[1]);
        o.y = pack_bf16(acc[2], acc[3]);
        o.z = pack_bf16(acc[4], acc[5]);
        o.w = pack_bf16(acc[6], acc[7]);
        *reinterpret_cast<uint4*>(y + lane * 4) = o;
    }
}

// stage 2: side = A@ego (int8) + p2@h1 + l2@h2 (bf16)   (output fp32)
__global__ __launch_bounds__(256) void spmm_stage2_kernel(
    const int* __restrict__ rp, const int2* __restrict__ cv,
    const unsigned* __restrict__ ego_q,
    const unsigned* __restrict__ h1, const unsigned* __restrict__ h2,
    float* __restrict__ side)
{
    int wid = (blockIdx.x * 256 + threadIdx.x) >> 6;
    int lane = threadIdx.x & 63;
    if (wid >= N_ENT) return;

    float acc[8] = {0, 0, 0, 0, 0, 0, 0, 0};
    walk_row_i8(cv, rp[RB_A  + wid], rp[RB_A  + wid + 1], lane, ego_q, acc);
    walk_row_bf(cv, rp[RB_P2 + wid], rp[RB_P2 + wid + 1], lane, h1, acc);
    walk_row_bf(cv, rp[RB_L2 + wid], rp[RB_L2 + wid + 1], lane, h2, acc);
    reduce_groups(acc);

    if (lane < 16) {
        float* yp = side + (long long)wid * DD + (lane & 15) * 8;
        float4 a0 = make_float4(acc[0], acc[1], acc[2], acc[3]);
        float4 a1 = make_float4(acc[4], acc[5], acc[6], acc[7]);
        *reinterpret_cast<float4*>(yp)     = a0;
        *reinterpret_cast<float4*>(yp + 4) = a1;
    }
}

// ---------------- MFMA dense epilogue (512 threads, 16 rows/wave) ----------------
union BfFrag { unsigned u[4]; bf16x8 v; };

__global__ __launch_bounds__(512, 4) void dense_mfma_kernel(
    const float* __restrict__ ego, const float* __restrict__ side,
    const float* __restrict__ W1, const float* __restrict__ b1,
    const float* __restrict__ W2, const float* __restrict__ b2,
    float* __restrict__ out)
{
    __shared__ unsigned Wb1[8192];   // 32 KB: W1 bf16, swizzled
    __shared__ unsigned Wb2[8192];   // 32 KB: W2 bf16, swizzled

    const int tid = threadIdx.x;

    for (int idx = tid; idx < 8192; idx += 512) {
        int row = idx >> 6, pc = idx & 63;
        unsigned pk1 = pack_bf16(W1[row * 128 + pc * 2], W1[row * 128 + pc * 2 + 1]);
        unsigned pk2 = pack_bf16(W2[row * 128 + pc * 2], W2[row * 128 + pc * 2 + 1]);
        int boff = row * 256 + ((pc * 4) ^ ((row & 7) << 4));
        *(unsigned*)((char*)Wb1 + boff) = pk1;
        *(unsigned*)((char*)Wb2 + boff) = pk2;
    }
    __syncthreads();

    const int wave = tid >> 6;   // 0..7
    const int lane = tid & 63;
    const int m    = lane & 15;
    const int kg   = lane >> 4;

    float bs[8], bb[8];
#pragma unroll
    for (int c = 0; c < 8; ++c) {
        bs[c] = b1[c * 16 + m];
        bb[c] = b2[c * 16 + m];
    }

    for (int wt = blockIdx.x * 8 + wave; wt < 6250; wt += gridDim.x * 8) {
        const long long r0 = (long long)(wt * 16 + m) * DD;

        f32x4 accS[8], accB[8];
#pragma unroll
        for (int c = 0; c < 8; ++c) { accS[c] = (f32x4)0.0f; accB[c] = (f32x4)0.0f; }

#pragma unroll 1
        for (int kk = 0; kk < 4; ++kk) {
            const int kb = kk * 32 + kg * 8;

            float4 ea = *(const float4*)(ego  + r0 + kb);
            float4 eb = *(const float4*)(ego  + r0 + kb + 4);
            float4 sa = *(const float4*)(side + r0 + kb);
            float4 sb = *(const float4*)(side + r0 + kb + 4);

            BfFrag aS, aB;
            aS.u[0] = pack_bf16(ea.x + sa.x, ea.y + sa.y);
            aS.u[1] = pack_bf16(ea.z + sa.z, ea.w + sa.w);
            aS.u[2] = pack_bf16(eb.x + sb.x, eb.y + sb.y);
            aS.u[3] = pack_bf16(eb.z + sb.z, eb.w + sb.w);
            aB.u[0] = pack_bf16(ea.x * sa.x, ea.y * sa.y);
            aB.u[1] = pack_bf16(ea.z * sa.z, ea.w * sa.w);
            aB.u[2] = pack_bf16(eb.x * sb.x, eb.y * sb.y);
            aB.u[3] = pack_bf16(eb.z * sb.z, eb.w * sb.w);

#pragma unroll
            for (int c = 0; c < 8; ++c) {
                int wrow = c * 16 + m;
                int boff = wrow * 256 + ((kk * 64 + (kg << 4)) ^ ((wrow & 7) << 4));
                bf16x8 w1 = *(const bf16x8*)((const char*)Wb1 + boff);
                bf16x8 w2 = *(const bf16x8*)((const char*)Wb2 + boff);
                accS[c] = __builtin_amdgcn_mfma_f32_16x16x32_bf16(aS.v, w1, accS[c], 0, 0, 0);
                accB[c] = __builtin_amdgcn_mfma_f32_16x16x32_bf16(aB.v, w2, accB[c], 0, 0, 0);
            }
        }

        // D mapping: col = lane&15 (=m), row = kg*4 + q
#pragma unroll
        for (int c = 0; c < 8; ++c) {
#pragma unroll
            for (int q = 0; q < 4; ++q) {
                int orow = wt * 16 + kg * 4 + q;
                out[(long long)orow * DD + c * 16 + m] =
                    lrelu(accS[c][q] + bs[c]) + lrelu(accB[c][q] + bb[c]);
            }
        }
    }
}

extern "C" void kernel_launch(void* const* d_in, const int* in_sizes, int n_in,
                              void* d_out, int out_size, void* d_ws, size_t ws_size,
                              hipStream_t stream)
{
    const float* ego = (const float*)d_in[0];
    const float* W1  = (const float*)d_in[16];
    const float* b1  = (const float*)d_in[17];
    const float* W2  = (const float*)d_in[18];
    const float* b2  = (const float*)d_in[19];

    BuildArgs a;
    a.rows[0] = (const int*)d_in[1];  a.cols[0] = (const int*)d_in[2];  a.vals[0] = (const float*)d_in[3];
    a.rows[1] = (const int*)d_in[4];  a.cols[1] = (const int*)d_in[5];  a.vals[1] = (const float*)d_in[6];
    a.rows[2] = (const int*)d_in[7];  a.cols[2] = (const int*)d_in[8];  a.vals[2] = (const float*)d_in[9];
    a.rows[3] = (const int*)d_in[10]; a.cols[3] = (const int*)d_in[11]; a.vals[3] = (const float*)d_in[12];
    a.rows[4] = (const int*)d_in[13]; a.cols[4] = (const int*)d_in[14]; a.vals[4] = (const float*)d_in[15];
    int nnz[5] = { in_sizes[1], in_sizes[4], in_sizes[7], in_sizes[10], in_sizes[13] };
    a.nnzbase[0] = 0;
    for (int s = 0; s < 5; ++s) a.nnzbase[s + 1] = a.nnzbase[s] + nnz[s];
    const int total = a.nnzbase[5];

    // ---- workspace carve (arena time-shares the side region) ----
    char* p = (char*)d_ws;
    float*    side     = (float*)p;
    int2*     arena    = (int2*)p;        p += (size_t)N_ENT * DD * 4;       // 51.2 MB (arena needs 48.8)
    unsigned* ego_q    = (unsigned*)p;    p += (size_t)N_ENT * 32 * 4;       // 12.8 MB (int8 rows, 128 B)
    float*    ego_scale= (float*)p;       p += (size_t)100096 * 4;           // 400 KB
    unsigned* h1       = (unsigned*)p;    p += (size_t)N_HE * 64 * 4;        // 5.12 MB (bf16 rows)
    unsigned* h2       = (unsigned*)p;    p += (size_t)N_HE * 64 * 4;        // 5.12 MB
    int2*     cv       = (int2*)p;        p += (size_t)total * 8;            // 44.8 MB
    int*      rp       = (int*)p;         p += 340224 * 4;
    int*      gcursor  = (int*)p;         p += 512 * 4;
    int*      bbase    = (int*)p;         p += 512 * 4;

    // build
    hipMemsetAsync(gcursor, 0, NB * sizeof(int), stream);
    quant_ego_kernel<<<(N_ENT * 32 + 255) / 256, 256, 0, stream>>>(ego, ego_q, ego_scale);
    const int nblk_part = (total + TILE - 1) / TILE;
    partition_kernel<<<nblk_part, 256, 0, stream>>>(a, gcursor, arena);
    bucket_scan_kernel<<<1, 512, 0, stream>>>(gcursor, bbase, rp);
    bucket_sort_kernel<<<NB, 256, 0, stream>>>(gcursor, bbase, arena, ego_scale, cv, rp);

    // spmm (arena region is dead from here; side reuses it)
    spmm_stage1_kernel<<<(2 * N_HE) / 4, 256, 0, stream>>>(rp, cv, ego_q, h1, h2);
    spmm_stage2_kernel<<<N_ENT / 4, 256, 0, stream>>>(rp, cv, ego_q, h1, h2, side);

    // dense epilogue (MFMA, 512-thread blocks)
    dense_mfma_kernel<<<782, 512, 0, stream>>>(ego, side, W1, b1, W2, b2, (float*)d_out);
}